// Round 2
// baseline (323.229 us; speedup 1.0000x reference)
//
#include <hip/hip_runtime.h>
#include <stdint.h>

#define B_  2
#define L_  2048
#define HD_ 1024
#define H_  16
#define D_  64

typedef unsigned short u16;
typedef __attribute__((ext_vector_type(8))) short bf16x8;
typedef __attribute__((ext_vector_type(4))) float f32x4;

#define MFMA16(a, b, c) __builtin_amdgcn_mfma_f32_16x16x32_bf16((a), (b), (c), 0, 0, 0)

__device__ __forceinline__ void gload16(const void* g, void* l) {
  __builtin_amdgcn_global_load_lds((const __attribute__((address_space(1))) void*)g,
                                   (__attribute__((address_space(3))) void*)l, 16, 0, 0);
}

__device__ __forceinline__ u16 f2bf(float f) {
  union { float f; uint32_t u; } c; c.f = f;
  uint32_t u = c.u + 0x7FFFu + ((c.u >> 16) & 1u);
  return (u16)(u >> 16);
}

// ---------------- cast f32 -> bf16 (8 elems/thread) ----------------
__global__ void cast_bf16_k(const float* __restrict__ in, u16* __restrict__ out, int n) {
  int i = (blockIdx.x * 256 + threadIdx.x) * 8;
  if (i >= n) return;
  float4 a = *(const float4*)(in + i);
  float4 b = *(const float4*)(in + i + 4);
  bf16x8 r;
  r[0] = (short)f2bf(a.x); r[1] = (short)f2bf(a.y); r[2] = (short)f2bf(a.z); r[3] = (short)f2bf(a.w);
  r[4] = (short)f2bf(b.x); r[5] = (short)f2bf(b.y); r[6] = (short)f2bf(b.z); r[7] = (short)f2bf(b.w);
  *(bf16x8*)(out + i) = r;
}

// ---------------- transpose + cast: dst[n][k] = bf16(src[k][n0+n]) ----------------
__global__ void transpose_cast_k(const float* __restrict__ src, u16* __restrict__ dst,
                                 int K, int Nfull, int n0) {
  __shared__ float tile[32][33];
  int t = threadIdx.x;
  int tc = t & 31, tr = t >> 5;
  int nb = blockIdx.x * 32, kb = blockIdx.y * 32;
#pragma unroll
  for (int i = 0; i < 4; i++)
    tile[tr + i * 8][tc] = src[(size_t)(kb + tr + i * 8) * Nfull + n0 + nb + tc];
  __syncthreads();
#pragma unroll
  for (int i = 0; i < 4; i++) {
    int nl = tr + i * 8;
    dst[(size_t)(nb + nl) * K + kb + tc] = f2bf(tile[tc][nl]);
  }
}

// ---------------- GEMM: C[m][n] = sum_k A[m][k]*Bt[n][k] + bias[n] ----------------
// A [M][K] bf16, Bt [N][K] bf16. 128x128 tile, BK=64, 4 waves (each 64x64).
// LDS rows are 128B (8 x 16B slots), slot s of row r stored at phys slot s^(r&7).
// epi 0: bf16 out [b,h,l,d] (Q).  epi 1: n<1024 -> K [b,h,l,d]; n>=1024 -> V^T [b,h,d,l].
// epi 2: f32 row-major + bias.
__global__ __launch_bounds__(256) void gemm_k(
    const u16* __restrict__ A, const u16* __restrict__ Bt,
    const float* __restrict__ bias, void* __restrict__ outp,
    int M, int N, int K, int epi)
{
  __shared__ char sA[128 * 128];
  __shared__ char sB[128 * 128];
  int t = threadIdx.x;
  int lane = t & 63, w = t >> 6;
  int g = lane >> 4, l15 = lane & 15;
  int wr = w >> 1, wc = w & 1;
  int bm = blockIdx.y * 128, bn = blockIdx.x * 128;

  f32x4 zero = {0.f, 0.f, 0.f, 0.f};
  f32x4 acc[4][4];
#pragma unroll
  for (int mi = 0; mi < 4; mi++)
#pragma unroll
    for (int ni = 0; ni < 4; ni++) acc[mi][ni] = zero;

  int nkt = K >> 6;
  for (int kt = 0; kt < nkt; kt++) {
    int k0 = kt << 6;
    __syncthreads();
#pragma unroll
    for (int it = 0; it < 4; it++) {
      int c = it * 256 + t;           // 0..1023 16B-chunks per matrix
      int r = c >> 3, sp = c & 7;
      int off = (sp ^ (r & 7)) << 4;  // pre-swizzled global source (T2 both-sides rule)
      gload16((const char*)(A + (size_t)(bm + r) * K + k0) + off, (char*)sA + c * 16);
      gload16((const char*)(Bt + (size_t)(bn + r) * K + k0) + off, (char*)sB + c * 16);
    }
    __syncthreads();
#pragma unroll
    for (int kc = 0; kc < 2; kc++) {
      bf16x8 af[4], bfr[4];
#pragma unroll
      for (int mi = 0; mi < 4; mi++) {
        int r = wr * 64 + mi * 16 + l15;
        af[mi] = *(const bf16x8*)(sA + r * 128 + (((kc * 4 + g) ^ (r & 7)) << 4));
      }
#pragma unroll
      for (int ni = 0; ni < 4; ni++) {
        int r = wc * 64 + ni * 16 + l15;
        bfr[ni] = *(const bf16x8*)(sB + r * 128 + (((kc * 4 + g) ^ (r & 7)) << 4));
      }
#pragma unroll
      for (int mi = 0; mi < 4; mi++)
#pragma unroll
        for (int ni = 0; ni < 4; ni++)
          acc[mi][ni] = MFMA16(af[mi], bfr[ni], acc[mi][ni]);
    }
  }

  float bv[4];
#pragma unroll
  for (int ni = 0; ni < 4; ni++) bv[ni] = bias[bn + wc * 64 + ni * 16 + l15];

  if (epi == 2) {
    float* fo = (float*)outp;
#pragma unroll
    for (int mi = 0; mi < 4; mi++)
#pragma unroll
      for (int ni = 0; ni < 4; ni++) {
        int n = bn + wc * 64 + ni * 16 + l15;
#pragma unroll
        for (int r = 0; r < 4; r++) {
          int m = bm + wr * 64 + mi * 16 + g * 4 + r;
          fo[(size_t)m * N + n] = acc[mi][ni][r] + bv[ni];
        }
      }
  } else {
    u16* ob = (u16*)outp;
#pragma unroll
    for (int mi = 0; mi < 4; mi++)
#pragma unroll
      for (int ni = 0; ni < 4; ni++) {
        int n = bn + wc * 64 + ni * 16 + l15;
        int kv = n >> 10;          // 0 for epi0 (N=1024)
        int hh = (n >> 6) & 15;
        int dd = n & 63;
        int m0 = bm + wr * 64 + mi * 16 + g * 4;
        int bb = m0 >> 11, lq0 = m0 & 2047;
        if (epi == 1 && kv == 1) {
          // V stored TRANSPOSED: [b,h,d,l]; r -> lq consecutive -> one 8B store
          ushort4 pk;
          pk.x = f2bf(acc[mi][ni][0] + bv[ni]);
          pk.y = f2bf(acc[mi][ni][1] + bv[ni]);
          pk.z = f2bf(acc[mi][ni][2] + bv[ni]);
          pk.w = f2bf(acc[mi][ni][3] + bv[ni]);
          size_t idx = (size_t)(B_ * H_ * L_ * D_) +
                       (((size_t)(bb * H_ + hh) * D_ + dd) * L_ + lq0);
          *(ushort4*)(ob + idx) = pk;
        } else {
#pragma unroll
          for (int r = 0; r < 4; r++) {
            size_t idx = (((size_t)(bb * H_ + hh) * L_ + lq0 + r) * D_) + dd;
            ob[idx] = f2bf(acc[mi][ni][r] + bv[ni]);
          }
        }
      }
  }
}

// ---------------- flash attention: swapped operands, no LDS, no barriers ----------------
// grid (32,16,2), 4 waves x 16 q each. S^T = mfma(K,Q): lane owns q=l15 column;
// online softmax is lane-scalar + 2 shuffles. PV: O^T = mfma(V^T, P^T) with V^T
// fragments straight from global [b,h,d,l]; P^T B-frag built via 8 shfl per K=32.
__global__ __launch_bounds__(256) void attn_k(
    const u16* __restrict__ Qb, const u16* __restrict__ Kb, const u16* __restrict__ Vt,
    const unsigned char* __restrict__ pad, u16* __restrict__ Ob)
{
  int t = threadIdx.x, lane = t & 63, w = t >> 6, g = lane >> 4, l15 = lane & 15;
  int qb = (int)gridDim.x - 1 - (int)blockIdx.x;  // heavy causal blocks first
  int h = blockIdx.y, b = blockIdx.z, bh = b * H_ + h;
  int q0w = qb * 64 + w * 16;
  int q = q0w + l15;                               // this lane's q column

  const u16* Qrow = Qb + ((size_t)bh * L_ + q) * D_ + g * 8;
  bf16x8 qf0 = *(const bf16x8*)(Qrow);             // d = g*8..+7
  bf16x8 qf1 = *(const bf16x8*)(Qrow + 32);        // d = 32+g*8..+7
  const u16* Kg = Kb + (size_t)bh * L_ * D_ + (size_t)l15 * D_ + g * 8;
  const u16* Vg = Vt + (size_t)bh * D_ * L_ + (size_t)l15 * L_ + g * 8;
  const unsigned char* pdb = pad + b * L_;

  f32x4 zero = {0.f, 0.f, 0.f, 0.f};
  f32x4 oacc[4];
#pragma unroll
  for (int db = 0; db < 4; db++) oacc[db] = zero;
  float mrun = -1e30f, lrun = 0.f;

  int kmax1 = q0w + 16;                            // exclusive key bound for this wave
  int trips = (kmax1 + 63) >> 6;

  for (int kt = 0; kt < trips; kt++) {
    int kt0 = kt << 6;
    int ns = (kmax1 - kt0 + 15) >> 4; if (ns > 4) ns = 4;   // live 16-key sub-tiles

    float sc[4][4];
#pragma unroll
    for (int s = 0; s < 4; s++) {
      if (s < ns) {
        int kb = kt0 + s * 16;
        const u16* kp = Kg + (size_t)kb * D_;
        bf16x8 kf0 = *(const bf16x8*)(kp);
        bf16x8 kf1 = *(const bf16x8*)(kp + 32);
        uint32_t pb = *(const uint32_t*)(pdb + kb + 4 * g);
        f32x4 st = zero;
        st = MFMA16(kf0, qf0, st);
        st = MFMA16(kf1, qf1, st);
#pragma unroll
        for (int r = 0; r < 4; r++) {
          int key = kb + 4 * g + r;
          bool msk = (key > q) || ((pb >> (8 * r)) & 0xffu);
          sc[s][r] = msk ? -1e30f : st[r] * 0.125f;
        }
      } else {
#pragma unroll
        for (int r = 0; r < 4; r++) sc[s][r] = -1e30f;
      }
    }

    // online softmax (per-lane scalar m,l; reduce across the 4 g-groups only)
    float mt = sc[0][0];
#pragma unroll
    for (int s = 0; s < 4; s++)
#pragma unroll
      for (int r = 0; r < 4; r++) mt = fmaxf(mt, sc[s][r]);
    mt = fmaxf(mt, __shfl_xor(mt, 16));
    mt = fmaxf(mt, __shfl_xor(mt, 32));
    float mnew = fmaxf(mrun, mt);
    float al = __expf(mrun - mnew);
    mrun = mnew;

    float rs = 0.f;
    uint32_t psW[4][2];
#pragma unroll
    for (int s = 0; s < 4; s++) {
      float p0 = __expf(sc[s][0] - mnew);
      float p1 = __expf(sc[s][1] - mnew);
      float p2 = __expf(sc[s][2] - mnew);
      float p3 = __expf(sc[s][3] - mnew);
      rs += (p0 + p1) + (p2 + p3);
      psW[s][0] = (uint32_t)f2bf(p0) | ((uint32_t)f2bf(p1) << 16);
      psW[s][1] = (uint32_t)f2bf(p2) | ((uint32_t)f2bf(p3) << 16);
    }
    rs += __shfl_xor(rs, 16);
    rs += __shfl_xor(rs, 32);
    lrun = lrun * al + rs;
#pragma unroll
    for (int db = 0; db < 4; db++)
#pragma unroll
      for (int r = 0; r < 4; r++) oacc[db][r] *= al;

    // P^T B-frag exchange + PV (O^T += V^T . P^T)
#pragma unroll
    for (int kc = 0; kc < 2; kc++) {
      if (2 * kc < ns) {
        int srcA = ((g & 1) << 5) + l15;   // lane holding keys 8*(g&1)+0..3 of sub-tile s'
        int srcB = srcA + 16;              // keys 8*(g&1)+4..7
        uint32_t a0 = psW[kc * 2][0], a1 = psW[kc * 2][1];
        uint32_t b0 = psW[kc * 2 + 1][0], b1 = psW[kc * 2 + 1][1];
        uint32_t hA0 = __shfl(a0, srcA), hA1 = __shfl(a1, srcA);
        uint32_t hB0 = __shfl(b0, srcA), hB1 = __shfl(b1, srcA);
        uint32_t iA0 = __shfl(a0, srcB), iA1 = __shfl(a1, srcB);
        uint32_t iB0 = __shfl(b0, srcB), iB1 = __shfl(b1, srcB);
        int hi = g >> 1;                   // selects sub-tile s' = kc*2 + hi
        union { bf16x8 v; uint32_t u[4]; } pf;
        pf.u[0] = hi ? hB0 : hA0;
        pf.u[1] = hi ? hB1 : hA1;
        pf.u[2] = hi ? iB0 : iA0;
        pf.u[3] = hi ? iB1 : iA1;
        const u16* vp = Vg + kt0 + kc * 32;
#pragma unroll
        for (int db = 0; db < 4; db++) {
          bf16x8 vf = *(const bf16x8*)(vp + (size_t)(db * 16) * L_);
          oacc[db] = MFMA16(vf, pf.v, oacc[db]);
        }
      }
    }
  }

  // epilogue: lane holds O^T[d = db*16 + g*4 + r][q]; 8B packed stores
  float rl = 1.0f / lrun;
  u16* op = Ob + ((size_t)b * L_ + q) * HD_ + h * D_ + g * 4;
#pragma unroll
  for (int db = 0; db < 4; db++) {
    ushort4 pk;
    pk.x = f2bf(oacc[db][0] * rl);
    pk.y = f2bf(oacc[db][1] * rl);
    pk.z = f2bf(oacc[db][2] * rl);
    pk.w = f2bf(oacc[db][3] * rl);
    *(ushort4*)(op + db * 16) = pk;
  }
}

extern "C" void kernel_launch(void* const* d_in, const int* in_sizes, int n_in,
                              void* d_out, int out_size, void* d_ws, size_t ws_size,
                              hipStream_t stream) {
  const float* x      = (const float*)d_in[0];
  const float* y      = (const float*)d_in[1];
  const unsigned char* mask = (const unsigned char*)d_in[2];
  const float* Wq_w   = (const float*)d_in[3];
  const float* Wq_b   = (const float*)d_in[4];
  const float* Wkv_w  = (const float*)d_in[5];
  const float* Wkv_b  = (const float*)d_in[6];
  const float* proj_w = (const float*)d_in[7];
  const float* proj_b = (const float*)d_in[8];

  char* ws = (char*)d_ws;
  u16* xb   = (u16*)(ws);                        // 8 MB  (reused as Ob after GEMM1)
  u16* yb   = (u16*)(ws + (size_t)(8  << 20));   // 8 MB
  u16* Wqt  = (u16*)(ws + (size_t)(16 << 20));   // 2 MB
  u16* Wkvt = (u16*)(ws + (size_t)(18 << 20));   // 4 MB
  u16* Wpt  = (u16*)(ws + (size_t)(22 << 20));   // 2 MB
  u16* Qb   = (u16*)(ws + (size_t)(24 << 20));   // 8 MB
  u16* Kb   = (u16*)(ws + (size_t)(32 << 20));   // 8 MB (V^T follows contiguously)
  u16* Vtb  = (u16*)(ws + (size_t)(40 << 20));   // 8 MB, layout [b,h,d,l]
  u16* Ob   = xb;

  hipLaunchKernelGGL(cast_bf16_k, dim3(2048), dim3(256), 0, stream, x, xb, B_ * L_ * HD_);
  hipLaunchKernelGGL(cast_bf16_k, dim3(2048), dim3(256), 0, stream, y, yb, B_ * L_ * HD_);
  hipLaunchKernelGGL(transpose_cast_k, dim3(32, 32), dim3(256), 0, stream, Wq_w, Wqt, 1024, 1024, 0);
  hipLaunchKernelGGL(transpose_cast_k, dim3(64, 32), dim3(256), 0, stream, Wkv_w, Wkvt, 1024, 2048, 0);
  hipLaunchKernelGGL(transpose_cast_k, dim3(32, 32), dim3(256), 0, stream, proj_w, Wpt, 1024, 1024, 0);
  // Q = xb @ Wq + b  -> [b,h,l,d] bf16
  hipLaunchKernelGGL(gemm_k, dim3(8, 32), dim3(256), 0, stream,
                     xb, Wqt, Wq_b, (void*)Qb, 4096, 1024, 1024, 0);
  // KV = yb @ Wkv + b -> K [b,h,l,d], V^T [b,h,d,l]
  hipLaunchKernelGGL(gemm_k, dim3(16, 32), dim3(256), 0, stream,
                     yb, Wkvt, Wkv_b, (void*)Kb, 4096, 2048, 1024, 1);
  hipLaunchKernelGGL(attn_k, dim3(L_ / 64, H_, B_), dim3(256), 0, stream, Qb, Kb, Vtb, mask, Ob);
  // out = Ob @ proj + b -> f32
  hipLaunchKernelGGL(gemm_k, dim3(8, 32), dim3(256), 0, stream,
                     Ob, Wpt, proj_b, d_out, 4096, 1024, 1024, 2);
}

// Round 3
// 182.995 us; speedup vs baseline: 1.7663x; 1.7663x over previous
//
#include <hip/hip_runtime.h>
#include <stdint.h>

#define B_  2
#define L_  2048
#define HD_ 1024
#define H_  16
#define D_  64

typedef unsigned short u16;
typedef __attribute__((ext_vector_type(8))) short bf16x8;
typedef __attribute__((ext_vector_type(4))) float f32x4;

#define MFMA16(a, b, c) __builtin_amdgcn_mfma_f32_16x16x32_bf16((a), (b), (c), 0, 0, 0)

__device__ __forceinline__ void gload16(const void* g, void* l) {
  __builtin_amdgcn_global_load_lds((const __attribute__((address_space(1))) void*)g,
                                   (__attribute__((address_space(3))) void*)l, 16, 0, 0);
}

__device__ __forceinline__ u16 f2bf(float f) {
  union { float f; uint32_t u; } c; c.f = f;
  uint32_t u = c.u + 0x7FFFu + ((c.u >> 16) & 1u);
  return (u16)(u >> 16);
}

__device__ __forceinline__ uint32_t cvt_pk_bf16(float lo, float hi) {
  uint32_t r;
  asm("v_cvt_pk_bf16_f32 %0, %1, %2" : "=v"(r) : "v"(lo), "v"(hi));
  return r;
}

// ---------------- cast f32 -> bf16 (8 elems/thread) ----------------
__global__ void cast_bf16_k(const float* __restrict__ in, u16* __restrict__ out, int n) {
  int i = (blockIdx.x * 256 + threadIdx.x) * 8;
  if (i >= n) return;
  float4 a = *(const float4*)(in + i);
  float4 b = *(const float4*)(in + i + 4);
  bf16x8 r;
  r[0] = (short)f2bf(a.x); r[1] = (short)f2bf(a.y); r[2] = (short)f2bf(a.z); r[3] = (short)f2bf(a.w);
  r[4] = (short)f2bf(b.x); r[5] = (short)f2bf(b.y); r[6] = (short)f2bf(b.z); r[7] = (short)f2bf(b.w);
  *(bf16x8*)(out + i) = r;
}

// ---------------- transpose + cast: dst[n][k] = bf16(src[k][n0+n]) ----------------
__global__ void transpose_cast_k(const float* __restrict__ src, u16* __restrict__ dst,
                                 int K, int Nfull, int n0) {
  __shared__ float tile[32][33];
  int t = threadIdx.x;
  int tc = t & 31, tr = t >> 5;
  int nb = blockIdx.x * 32, kb = blockIdx.y * 32;
#pragma unroll
  for (int i = 0; i < 4; i++)
    tile[tr + i * 8][tc] = src[(size_t)(kb + tr + i * 8) * Nfull + n0 + nb + tc];
  __syncthreads();
#pragma unroll
  for (int i = 0; i < 4; i++) {
    int nl = tr + i * 8;
    dst[(size_t)(nb + nl) * K + kb + tc] = f2bf(tile[tc][nl]);
  }
}

// ---------------- GEMM: C[m][n] = sum_k A[m][k]*Bt[n][k] + bias[n] ----------------
// A [M][K] bf16, Bt [N][K] bf16. 128x128 tile, BK=64, 4 waves (each 64x64).
// LDS rows are 128B (8 x 16B slots), slot s of row r stored at phys slot s^(r&7).
// epi 0: bf16 out [b,h,l,d] (Q).  epi 1: n<1024 -> K [b,h,l,d]; n>=1024 -> V^T [b,h,d,l].
// epi 2: f32 row-major + bias.
__global__ __launch_bounds__(256) void gemm_k(
    const u16* __restrict__ A, const u16* __restrict__ Bt,
    const float* __restrict__ bias, void* __restrict__ outp,
    int M, int N, int K, int epi)
{
  __shared__ char sA[128 * 128];
  __shared__ char sB[128 * 128];
  int t = threadIdx.x;
  int lane = t & 63, w = t >> 6;
  int g = lane >> 4, l15 = lane & 15;
  int wr = w >> 1, wc = w & 1;
  int bm = blockIdx.y * 128, bn = blockIdx.x * 128;

  f32x4 zero = {0.f, 0.f, 0.f, 0.f};
  f32x4 acc[4][4];
#pragma unroll
  for (int mi = 0; mi < 4; mi++)
#pragma unroll
    for (int ni = 0; ni < 4; ni++) acc[mi][ni] = zero;

  int nkt = K >> 6;
  for (int kt = 0; kt < nkt; kt++) {
    int k0 = kt << 6;
    __syncthreads();
#pragma unroll
    for (int it = 0; it < 4; it++) {
      int c = it * 256 + t;           // 0..1023 16B-chunks per matrix
      int r = c >> 3, sp = c & 7;
      int off = (sp ^ (r & 7)) << 4;  // pre-swizzled global source (T2 both-sides rule)
      gload16((const char*)(A + (size_t)(bm + r) * K + k0) + off, (char*)sA + c * 16);
      gload16((const char*)(Bt + (size_t)(bn + r) * K + k0) + off, (char*)sB + c * 16);
    }
    __syncthreads();
#pragma unroll
    for (int kc = 0; kc < 2; kc++) {
      bf16x8 af[4], bfr[4];
#pragma unroll
      for (int mi = 0; mi < 4; mi++) {
        int r = wr * 64 + mi * 16 + l15;
        af[mi] = *(const bf16x8*)(sA + r * 128 + (((kc * 4 + g) ^ (r & 7)) << 4));
      }
#pragma unroll
      for (int ni = 0; ni < 4; ni++) {
        int r = wc * 64 + ni * 16 + l15;
        bfr[ni] = *(const bf16x8*)(sB + r * 128 + (((kc * 4 + g) ^ (r & 7)) << 4));
      }
#pragma unroll
      for (int mi = 0; mi < 4; mi++)
#pragma unroll
        for (int ni = 0; ni < 4; ni++)
          acc[mi][ni] = MFMA16(af[mi], bfr[ni], acc[mi][ni]);
    }
  }

  float bv[4];
#pragma unroll
  for (int ni = 0; ni < 4; ni++) bv[ni] = bias[bn + wc * 64 + ni * 16 + l15];

  if (epi == 2) {
    float* fo = (float*)outp;
#pragma unroll
    for (int mi = 0; mi < 4; mi++)
#pragma unroll
      for (int ni = 0; ni < 4; ni++) {
        int n = bn + wc * 64 + ni * 16 + l15;
#pragma unroll
        for (int r = 0; r < 4; r++) {
          int m = bm + wr * 64 + mi * 16 + g * 4 + r;
          fo[(size_t)m * N + n] = acc[mi][ni][r] + bv[ni];
        }
      }
  } else {
    u16* ob = (u16*)outp;
#pragma unroll
    for (int mi = 0; mi < 4; mi++)
#pragma unroll
      for (int ni = 0; ni < 4; ni++) {
        int n = bn + wc * 64 + ni * 16 + l15;
        int kv = n >> 10;          // 0 for epi0 (N=1024)
        int hh = (n >> 6) & 15;
        int dd = n & 63;
        int m0 = bm + wr * 64 + mi * 16 + g * 4;
        int bb = m0 >> 11, lq0 = m0 & 2047;
        if (epi == 1 && kv == 1) {
          // V stored TRANSPOSED: [b,h,d,l]; r -> lq consecutive -> one 8B store
          ushort4 pk;
          pk.x = f2bf(acc[mi][ni][0] + bv[ni]);
          pk.y = f2bf(acc[mi][ni][1] + bv[ni]);
          pk.z = f2bf(acc[mi][ni][2] + bv[ni]);
          pk.w = f2bf(acc[mi][ni][3] + bv[ni]);
          size_t idx = (size_t)(B_ * H_ * L_ * D_) +
                       (((size_t)(bb * H_ + hh) * D_ + dd) * L_ + lq0);
          *(ushort4*)(ob + idx) = pk;
        } else {
#pragma unroll
          for (int r = 0; r < 4; r++) {
            size_t idx = (((size_t)(bb * H_ + hh) * L_ + lq0 + r) * D_) + dd;
            ob[idx] = f2bf(acc[mi][ni][r] + bv[ni]);
          }
        }
      }
  }
}

// ---------------- flash attention v3 ----------------
// grid (16,16,2), 4 waves x 32 q-rows = 128 q/block. KVBLK=64 keys double-buffered
// in LDS via global_load_lds (shared by all waves). Swapped S^T=mfma(K,Q): lane owns
// q-column, softmax lane-scalar + 2 shfl_xor per col-group. P routed through a
// per-wave swizzled LDS buffer (same-wave in-order, no barrier). 2-phase pipeline:
// stage(next) issued before compute(cur), one barrier per tile.
__global__ __launch_bounds__(256, 2) void attn_k(
    const u16* __restrict__ Qb, const u16* __restrict__ Kb, const u16* __restrict__ Vt,
    const unsigned char* __restrict__ pad, u16* __restrict__ Ob)
{
  __shared__ char sK[2][8192];   // [buf][key 0..63][128B row], slot s at phys s^(key&7)
  __shared__ char sV[2][8192];   // [buf][d 0..63][128B row = 64 keys], slot s^(d&7)
  __shared__ char sP[4][4096];   // per-wave P^T: [row c*16+q15][128B = 64 keys], s^(q15&7)
  int t = threadIdx.x, lane = t & 63, w = t >> 6, g = lane >> 4, l15 = lane & 15;
  int qb = 15 - (int)blockIdx.x;  // heavy causal blocks dispatched earliest
  int h = blockIdx.y, b = blockIdx.z, bh = b * H_ + h;
  int q0 = qb * 128;
  int qw0 = q0 + w * 32;
  int bound = qw0 + 31;           // last q-row this wave owns

  const u16* Kbh = Kb + (size_t)bh * L_ * D_;
  const u16* Vbh = Vt + (size_t)bh * D_ * L_;
  const unsigned char* pdb = pad + b * L_;

  // Q fragments, both 16-col groups: qf[c][dc] covers d = dc*32 + g*8 .. +7
  bf16x8 qf[2][2];
#pragma unroll
  for (int c = 0; c < 2; c++) {
    const u16* qp = Qb + ((size_t)bh * L_ + qw0 + c * 16 + l15) * D_ + g * 8;
    qf[c][0] = *(const bf16x8*)qp;
    qf[c][1] = *(const bf16x8*)(qp + 32);
  }

  f32x4 zero = {0.f, 0.f, 0.f, 0.f};
  f32x4 oacc[2][4];
#pragma unroll
  for (int c = 0; c < 2; c++)
#pragma unroll
    for (int db = 0; db < 4; db++) oacc[c][db] = zero;
  float mrun[2] = {-1e30f, -1e30f}, lrun[2] = {0.f, 0.f};

  const float SCL = 0.125f * 1.44269504089f;  // scale * log2(e); exp via v_exp_f32
  int nkt = 2 * qb + 2;

  // staging: 2 chunks/thread/matrix; chunk cc -> row cc>>3, 16B slot cc&7 (src pre-swizzled)
#define STAGE(bufi, kt0s) do {                                                        \
    _Pragma("unroll")                                                                 \
    for (int ii = 0; ii < 2; ii++) {                                                  \
      int cc = ii * 256 + t; int rr = cc >> 3, sp = cc & 7;                           \
      int so = (sp ^ (rr & 7)) << 4;                                                  \
      gload16((const char*)(Kbh + (size_t)((kt0s) + rr) * D_) + so, sK[bufi] + cc * 16); \
      gload16((const char*)(Vbh + (size_t)rr * L_ + (kt0s)) + so, sV[bufi] + cc * 16);   \
    } } while (0)

  STAGE(0, 0);
  __syncthreads();                 // compiler drains vmcnt before s_barrier
  int buf = 0;

  for (int kt = 0; kt < nkt; kt++) {
    int kt0 = kt << 6;
    if (kt + 1 < nkt) STAGE(buf ^ 1, (kt + 1) << 6);  // prefetch next tile (T3/T14)

    if (kt0 <= bound) {
      // ---- S^T = mfma(K, Q): lane (g,l15) gets keys kb+4g+r at q-col l15 ----
      float sc[2][4][4];
#pragma unroll
      for (int s = 0; s < 4; s++) {
        int kb = kt0 + s * 16;
        bool live = (kb <= bound);
        f32x4 st0 = zero, st1 = zero;
        uint32_t pb = 0;
        if (live) {
          int R = s * 16 + l15, sw = l15 & 7;
          bf16x8 kf0 = *(const bf16x8*)(sK[buf] + R * 128 + ((g ^ sw) << 4));
          bf16x8 kf1 = *(const bf16x8*)(sK[buf] + R * 128 + (((4 + g) ^ sw) << 4));
          st0 = MFMA16(kf0, qf[0][0], st0); st0 = MFMA16(kf1, qf[0][1], st0);
          st1 = MFMA16(kf0, qf[1][0], st1); st1 = MFMA16(kf1, qf[1][1], st1);
          pb = *(const uint32_t*)(pdb + kb + 4 * g);
        }
#pragma unroll
        for (int r = 0; r < 4; r++) {
          int key = kb + 4 * g + r;
          bool pm = (pb >> (8 * r)) & 0xffu;
#pragma unroll
          for (int c = 0; c < 2; c++) {
            int q = qw0 + c * 16 + l15;
            bool msk = !live || pm || (key > q);
            float v = c ? st1[r] : st0[r];
            sc[c][s][r] = msk ? -1e30f : v * SCL;
          }
        }
      }

      // ---- online softmax + P write (per 16-col group) ----
#pragma unroll
      for (int c = 0; c < 2; c++) {
        float m01 = fmaxf(fmaxf(sc[c][0][0], sc[c][0][1]), fmaxf(sc[c][0][2], sc[c][0][3]));
        float m11 = fmaxf(fmaxf(sc[c][1][0], sc[c][1][1]), fmaxf(sc[c][1][2], sc[c][1][3]));
        float m21 = fmaxf(fmaxf(sc[c][2][0], sc[c][2][1]), fmaxf(sc[c][2][2], sc[c][2][3]));
        float m31 = fmaxf(fmaxf(sc[c][3][0], sc[c][3][1]), fmaxf(sc[c][3][2], sc[c][3][3]));
        float mt = fmaxf(fmaxf(m01, m11), fmaxf(m21, m31));
        mt = fmaxf(mt, __shfl_xor(mt, 16));
        mt = fmaxf(mt, __shfl_xor(mt, 32));
        float mnew = fmaxf(mrun[c], mt);
        float al = __builtin_amdgcn_exp2f(mrun[c] - mnew);
        mrun[c] = mnew;
        float rs = 0.f;
        int prow = c * 16 + l15, psw = l15 & 7;
        char* pwb = sP[w] + prow * 128 + (g & 1) * 8;
#pragma unroll
        for (int s = 0; s < 4; s++) {
          float p0 = __builtin_amdgcn_exp2f(sc[c][s][0] - mnew);
          float p1 = __builtin_amdgcn_exp2f(sc[c][s][1] - mnew);
          float p2 = __builtin_amdgcn_exp2f(sc[c][s][2] - mnew);
          float p3 = __builtin_amdgcn_exp2f(sc[c][s][3] - mnew);
          rs += (p0 + p1) + (p2 + p3);
          uint32_t w0 = cvt_pk_bf16(p0, p1), w1 = cvt_pk_bf16(p2, p3);
          char* dst = pwb + (((2 * s + (g >> 1)) ^ psw) << 4);
          *(uint32_t*)dst = w0;
          *(uint32_t*)(dst + 4) = w1;
        }
        rs += __shfl_xor(rs, 16);
        rs += __shfl_xor(rs, 32);
        lrun[c] = lrun[c] * al + rs;
#pragma unroll
        for (int db = 0; db < 4; db++)
#pragma unroll
          for (int r = 0; r < 4; r++) oacc[c][db][r] *= al;
      }

      // ---- PV: O^T += V^T . P^T (A = V^T from LDS, B = P^T from per-wave LDS) ----
#pragma unroll
      for (int kc = 0; kc < 2; kc++) {
        if (kt0 + 32 * kc <= bound) {
          bf16x8 pf[2];
#pragma unroll
          for (int c = 0; c < 2; c++)
            pf[c] = *(const bf16x8*)(sP[w] + (c * 16 + l15) * 128 +
                                     (((4 * kc + g) ^ (l15 & 7)) << 4));
#pragma unroll
          for (int db = 0; db < 4; db++) {
            int dR = db * 16 + l15;
            bf16x8 vf = *(const bf16x8*)(sV[buf] + dR * 128 +
                                         (((4 * kc + g) ^ (dR & 7)) << 4));
            oacc[0][db] = MFMA16(vf, pf[0], oacc[0][db]);
            oacc[1][db] = MFMA16(vf, pf[1], oacc[1][db]);
          }
        }
      }
    }
    __syncthreads();   // drains staged vmcnt + protects buf flip
    buf ^= 1;
  }
#undef STAGE

  // epilogue: lane holds O^T[d = db*16 + g*4 + r][q = qw0 + c*16 + l15]
#pragma unroll
  for (int c = 0; c < 2; c++) {
    float rl = 1.0f / lrun[c];
    int q = qw0 + c * 16 + l15;
    u16* op = Ob + ((size_t)b * L_ + q) * HD_ + h * D_ + g * 4;
#pragma unroll
    for (int db = 0; db < 4; db++) {
      ushort4 pk;
      pk.x = f2bf(oacc[c][db][0] * rl);
      pk.y = f2bf(oacc[c][db][1] * rl);
      pk.z = f2bf(oacc[c][db][2] * rl);
      pk.w = f2bf(oacc[c][db][3] * rl);
      *(ushort4*)(op + db * 16) = pk;
    }
  }
}

extern "C" void kernel_launch(void* const* d_in, const int* in_sizes, int n_in,
                              void* d_out, int out_size, void* d_ws, size_t ws_size,
                              hipStream_t stream) {
  const float* x      = (const float*)d_in[0];
  const float* y      = (const float*)d_in[1];
  const unsigned char* mask = (const unsigned char*)d_in[2];
  const float* Wq_w   = (const float*)d_in[3];
  const float* Wq_b   = (const float*)d_in[4];
  const float* Wkv_w  = (const float*)d_in[5];
  const float* Wkv_b  = (const float*)d_in[6];
  const float* proj_w = (const float*)d_in[7];
  const float* proj_b = (const float*)d_in[8];

  char* ws = (char*)d_ws;
  u16* xb   = (u16*)(ws);                        // 8 MB  (reused as Ob after GEMM1)
  u16* yb   = (u16*)(ws + (size_t)(8  << 20));   // 8 MB
  u16* Wqt  = (u16*)(ws + (size_t)(16 << 20));   // 2 MB
  u16* Wkvt = (u16*)(ws + (size_t)(18 << 20));   // 4 MB
  u16* Wpt  = (u16*)(ws + (size_t)(22 << 20));   // 2 MB
  u16* Qb   = (u16*)(ws + (size_t)(24 << 20));   // 8 MB
  u16* Kb   = (u16*)(ws + (size_t)(32 << 20));   // 8 MB (V^T follows contiguously)
  u16* Vtb  = (u16*)(ws + (size_t)(40 << 20));   // 8 MB, layout [b,h,d,l]
  u16* Ob   = xb;

  hipLaunchKernelGGL(cast_bf16_k, dim3(2048), dim3(256), 0, stream, x, xb, B_ * L_ * HD_);
  hipLaunchKernelGGL(cast_bf16_k, dim3(2048), dim3(256), 0, stream, y, yb, B_ * L_ * HD_);
  hipLaunchKernelGGL(transpose_cast_k, dim3(32, 32), dim3(256), 0, stream, Wq_w, Wqt, 1024, 1024, 0);
  hipLaunchKernelGGL(transpose_cast_k, dim3(64, 32), dim3(256), 0, stream, Wkv_w, Wkvt, 1024, 2048, 0);
  hipLaunchKernelGGL(transpose_cast_k, dim3(32, 32), dim3(256), 0, stream, proj_w, Wpt, 1024, 1024, 0);
  // Q = xb @ Wq + b  -> [b,h,l,d] bf16
  hipLaunchKernelGGL(gemm_k, dim3(8, 32), dim3(256), 0, stream,
                     xb, Wqt, Wq_b, (void*)Qb, 4096, 1024, 1024, 0);
  // KV = yb @ Wkv + b -> K [b,h,l,d], V^T [b,h,d,l]
  hipLaunchKernelGGL(gemm_k, dim3(16, 32), dim3(256), 0, stream,
                     yb, Wkvt, Wkv_b, (void*)Kb, 4096, 2048, 1024, 1);
  hipLaunchKernelGGL(attn_k, dim3(16, H_, B_), dim3(256), 0, stream, Qb, Kb, Vtb, mask, Ob);
  // out = Ob @ proj + b -> f32
  hipLaunchKernelGGL(gemm_k, dim3(8, 32), dim3(256), 0, stream,
                     Ob, Wpt, proj_b, d_out, 4096, 1024, 1024, 2);
}

// Round 5
// 169.886 us; speedup vs baseline: 1.9026x; 1.0772x over previous
//
#include <hip/hip_runtime.h>
#include <stdint.h>

#define B_  2
#define L_  2048
#define HD_ 1024
#define H_  16
#define D_  64

typedef unsigned short u16;
typedef __attribute__((ext_vector_type(8))) short bf16x8;
typedef __attribute__((ext_vector_type(4))) float f32x4;

#define MFMA16(a, b, c) __builtin_amdgcn_mfma_f32_16x16x32_bf16((a), (b), (c), 0, 0, 0)

__device__ __forceinline__ void gload16(const void* g, void* l) {
  __builtin_amdgcn_global_load_lds((const __attribute__((address_space(1))) void*)g,
                                   (__attribute__((address_space(3))) void*)l, 16, 0, 0);
}

__device__ __forceinline__ u16 f2bf(float f) {
  union { float f; uint32_t u; } c; c.f = f;
  uint32_t u = c.u + 0x7FFFu + ((c.u >> 16) & 1u);
  return (u16)(u >> 16);
}

__device__ __forceinline__ uint32_t cvt_pk_bf16(float lo, float hi) {
  uint32_t r;
  asm("v_cvt_pk_bf16_f32 %0, %1, %2" : "=v"(r) : "v"(lo), "v"(hi));
  return r;
}

// ---------------- fused cast f32 -> bf16 for x and y (8 elems/thread) ----------------
__global__ void cast2_k(const float* __restrict__ x, const float* __restrict__ y,
                        u16* __restrict__ xb, u16* __restrict__ yb) {
  int bid = blockIdx.x;
  const float* in = bid < 2048 ? x : y;
  u16* out = bid < 2048 ? xb : yb;
  int i = ((bid & 2047) * 256 + threadIdx.x) * 8;   // 2048*256*8 == 4M exact
  float4 a = *(const float4*)(in + i);
  float4 b = *(const float4*)(in + i + 4);
  bf16x8 r;
  r[0] = (short)f2bf(a.x); r[1] = (short)f2bf(a.y); r[2] = (short)f2bf(a.z); r[3] = (short)f2bf(a.w);
  r[4] = (short)f2bf(b.x); r[5] = (short)f2bf(b.y); r[6] = (short)f2bf(b.z); r[7] = (short)f2bf(b.w);
  *(bf16x8*)(out + i) = r;
}

// ---------------- fused transpose+cast of all three weights: dst[n][k]=bf16(src[k][n]) ----
// z=0: Wq (N=1024), z=1: Wkv (N=2048), z=2: proj (N=1024). K=1024 for all.
__global__ void wtrans_k(const float* __restrict__ Wq, const float* __restrict__ Wkv,
                         const float* __restrict__ Wp,
                         u16* __restrict__ Wqt, u16* __restrict__ Wkvt, u16* __restrict__ Wpt) {
  int z = blockIdx.z;
  const float* src = z == 0 ? Wq : (z == 1 ? Wkv : Wp);
  u16* dst = z == 0 ? Wqt : (z == 1 ? Wkvt : Wpt);
  int Nfull = (z == 1) ? 2048 : 1024;
  int nb = blockIdx.x * 32;
  if (nb >= Nfull) return;               // block-uniform early out (before any barrier)
  __shared__ float tile[32][33];
  int t = threadIdx.x;
  int tc = t & 31, tr = t >> 5;
  int kb = blockIdx.y * 32;
#pragma unroll
  for (int i = 0; i < 4; i++)
    tile[tr + i * 8][tc] = src[(size_t)(kb + tr + i * 8) * Nfull + nb + tc];
  __syncthreads();
#pragma unroll
  for (int i = 0; i < 4; i++) {
    int nl = tr + i * 8;
    dst[(size_t)(nb + nl) * 1024 + kb + tc] = f2bf(tile[tc][nl]);
  }
}

// ---------------- shared GEMM body: C[m][n] = sum_k A[m][k]*Bt[n][k] + bias[n] ----
// K = 1024 fixed. 128x128 tile, BK=64, 4 waves. LDS rows 128B, slot s at phys s^(r&7).
// epi 0: bf16 out [b,h,l,d].  epi 1: n<1024 -> K [b,h,l,d]; n>=1024 -> V^T [b,h,d,l].
// epi 2: f32 row-major + bias (uses N).
__device__ __forceinline__ void gemm_body(
    char* sA, char* sB,
    const u16* __restrict__ A, const u16* __restrict__ Bt,
    const float* __restrict__ bias, void* __restrict__ outp,
    int N, int epi, int bm, int bn)
{
  int t = threadIdx.x;
  int lane = t & 63, w = t >> 6;
  int g = lane >> 4, l15 = lane & 15;
  int wr = w >> 1, wc = w & 1;

  f32x4 zero = {0.f, 0.f, 0.f, 0.f};
  f32x4 acc[4][4];
#pragma unroll
  for (int mi = 0; mi < 4; mi++)
#pragma unroll
    for (int ni = 0; ni < 4; ni++) acc[mi][ni] = zero;

  for (int kt = 0; kt < 16; kt++) {
    int k0 = kt << 6;
    __syncthreads();
#pragma unroll
    for (int it = 0; it < 4; it++) {
      int c = it * 256 + t;           // 0..1023 16B-chunks per matrix
      int r = c >> 3, sp = c & 7;
      int off = (sp ^ (r & 7)) << 4;  // pre-swizzled global source (T2 both-sides rule)
      gload16((const char*)(A + (size_t)(bm + r) * 1024 + k0) + off, sA + c * 16);
      gload16((const char*)(Bt + (size_t)(bn + r) * 1024 + k0) + off, sB + c * 16);
    }
    __syncthreads();
#pragma unroll
    for (int kc = 0; kc < 2; kc++) {
      bf16x8 af[4], bfr[4];
#pragma unroll
      for (int mi = 0; mi < 4; mi++) {
        int r = wr * 64 + mi * 16 + l15;
        af[mi] = *(const bf16x8*)(sA + r * 128 + (((kc * 4 + g) ^ (r & 7)) << 4));
      }
#pragma unroll
      for (int ni = 0; ni < 4; ni++) {
        int r = wc * 64 + ni * 16 + l15;
        bfr[ni] = *(const bf16x8*)(sB + r * 128 + (((kc * 4 + g) ^ (r & 7)) << 4));
      }
#pragma unroll
      for (int mi = 0; mi < 4; mi++)
#pragma unroll
        for (int ni = 0; ni < 4; ni++)
          acc[mi][ni] = MFMA16(af[mi], bfr[ni], acc[mi][ni]);
    }
  }

  float bv[4];
#pragma unroll
  for (int ni = 0; ni < 4; ni++) bv[ni] = bias[bn + wc * 64 + ni * 16 + l15];

  if (epi == 2) {
    float* fo = (float*)outp;
#pragma unroll
    for (int mi = 0; mi < 4; mi++)
#pragma unroll
      for (int ni = 0; ni < 4; ni++) {
        int n = bn + wc * 64 + ni * 16 + l15;
#pragma unroll
        for (int r = 0; r < 4; r++) {
          int m = bm + wr * 64 + mi * 16 + g * 4 + r;
          fo[(size_t)m * N + n] = acc[mi][ni][r] + bv[ni];
        }
      }
  } else {
    u16* ob = (u16*)outp;
#pragma unroll
    for (int mi = 0; mi < 4; mi++)
#pragma unroll
      for (int ni = 0; ni < 4; ni++) {
        int n = bn + wc * 64 + ni * 16 + l15;
        int kv = n >> 10;          // 0 for epi0 (N=1024)
        int hh = (n >> 6) & 15;
        int dd = n & 63;
        int m0 = bm + wr * 64 + mi * 16 + g * 4;
        int bb = m0 >> 11, lq0 = m0 & 2047;
        if (epi == 1 && kv == 1) {
          // V stored TRANSPOSED: [b,h,d,l]; r -> lq consecutive -> one 8B store
          ushort4 pk;
          pk.x = f2bf(acc[mi][ni][0] + bv[ni]);
          pk.y = f2bf(acc[mi][ni][1] + bv[ni]);
          pk.z = f2bf(acc[mi][ni][2] + bv[ni]);
          pk.w = f2bf(acc[mi][ni][3] + bv[ni]);
          size_t idx = (size_t)(B_ * H_ * L_ * D_) +
                       (((size_t)(bb * H_ + hh) * D_ + dd) * L_ + lq0);
          *(ushort4*)(ob + idx) = pk;
        } else {
#pragma unroll
          for (int r = 0; r < 4; r++) {
            size_t idx = (((size_t)(bb * H_ + hh) * L_ + lq0 + r) * D_) + dd;
            ob[idx] = f2bf(acc[mi][ni][r] + bv[ni]);
          }
        }
      }
  }
}

// fused Q + KV projection: grid (8+16, 32); bx<8 -> Q-GEMM, else KV-GEMM.
__global__ __launch_bounds__(256) void qkv_k(
    const u16* __restrict__ xb, const u16* __restrict__ yb,
    const u16* __restrict__ Wqt, const u16* __restrict__ Wkvt,
    const float* __restrict__ Wq_b, const float* __restrict__ Wkv_b,
    u16* __restrict__ Qout, u16* __restrict__ KVout)
{
  __shared__ char sA[128 * 128];
  __shared__ char sB[128 * 128];
  int bx = blockIdx.x, bm = blockIdx.y * 128;
  if (bx < 8)
    gemm_body(sA, sB, xb, Wqt, Wq_b, (void*)Qout, 1024, 0, bm, bx * 128);
  else
    gemm_body(sA, sB, yb, Wkvt, Wkv_b, (void*)KVout, 2048, 1, bm, (bx - 8) * 128);
}

// proj GEMM (epi2, f32 out)
__global__ __launch_bounds__(256) void gemm_k(
    const u16* __restrict__ A, const u16* __restrict__ Bt,
    const float* __restrict__ bias, void* __restrict__ outp, int N)
{
  __shared__ char sA[128 * 128];
  __shared__ char sB[128 * 128];
  gemm_body(sA, sB, A, Bt, bias, outp, N, 2, blockIdx.y * 128, blockIdx.x * 128);
}

// ---------------- flash attention (verbatim R2 body — the version that passed @91us) ----
// grid (16,16,2), 4 waves x 32 q-rows = 128 q/block. KVBLK=64 keys double-buffered
// in LDS via global_load_lds (shared by all waves). Swapped S^T=mfma(K,Q): lane owns
// q-column, softmax lane-scalar + 2 shfl_xor per col-group. P routed through a
// per-wave swizzled LDS buffer (same-wave in-order, no barrier). 2-phase pipeline:
// stage(next) issued before compute(cur), one barrier per tile.
__global__ __launch_bounds__(256, 2) void attn_k(
    const u16* __restrict__ Qb, const u16* __restrict__ Kb, const u16* __restrict__ Vt,
    const unsigned char* __restrict__ pad, u16* __restrict__ Ob)
{
  __shared__ char sK[2][8192];   // [buf][key 0..63][128B row], slot s at phys s^(key&7)
  __shared__ char sV[2][8192];   // [buf][d 0..63][128B row = 64 keys], slot s^(d&7)
  __shared__ char sP[4][4096];   // per-wave P^T: [row c*16+q15][128B = 64 keys], s^(q15&7)
  int t = threadIdx.x, lane = t & 63, w = t >> 6, g = lane >> 4, l15 = lane & 15;
  int qb = 15 - (int)blockIdx.x;  // heavy causal blocks dispatched earliest
  int h = blockIdx.y, b = blockIdx.z, bh = b * H_ + h;
  int q0 = qb * 128;
  int qw0 = q0 + w * 32;
  int bound = qw0 + 31;           // last q-row this wave owns

  const u16* Kbh = Kb + (size_t)bh * L_ * D_;
  const u16* Vbh = Vt + (size_t)bh * D_ * L_;
  const unsigned char* pdb = pad + b * L_;

  // Q fragments, both 16-col groups: qf[c][dc] covers d = dc*32 + g*8 .. +7
  bf16x8 qf[2][2];
#pragma unroll
  for (int c = 0; c < 2; c++) {
    const u16* qp = Qb + ((size_t)bh * L_ + qw0 + c * 16 + l15) * D_ + g * 8;
    qf[c][0] = *(const bf16x8*)qp;
    qf[c][1] = *(const bf16x8*)(qp + 32);
  }

  f32x4 zero = {0.f, 0.f, 0.f, 0.f};
  f32x4 oacc[2][4];
#pragma unroll
  for (int c = 0; c < 2; c++)
#pragma unroll
    for (int db = 0; db < 4; db++) oacc[c][db] = zero;
  float mrun[2] = {-1e30f, -1e30f}, lrun[2] = {0.f, 0.f};

  const float SCL = 0.125f * 1.44269504089f;  // scale * log2(e); exp via v_exp_f32
  int nkt = 2 * qb + 2;

  // staging: 2 chunks/thread/matrix; chunk cc -> row cc>>3, 16B slot cc&7 (src pre-swizzled)
#define STAGE(bufi, kt0s) do {                                                        \
    _Pragma("unroll")                                                                 \
    for (int ii = 0; ii < 2; ii++) {                                                  \
      int cc = ii * 256 + t; int rr = cc >> 3, sp = cc & 7;                           \
      int so = (sp ^ (rr & 7)) << 4;                                                  \
      gload16((const char*)(Kbh + (size_t)((kt0s) + rr) * D_) + so, sK[bufi] + cc * 16); \
      gload16((const char*)(Vbh + (size_t)rr * L_ + (kt0s)) + so, sV[bufi] + cc * 16);   \
    } } while (0)

  STAGE(0, 0);
  __syncthreads();                 // compiler drains vmcnt before s_barrier
  int buf = 0;

  for (int kt = 0; kt < nkt; kt++) {
    int kt0 = kt << 6;
    if (kt + 1 < nkt) STAGE(buf ^ 1, (kt + 1) << 6);  // prefetch next tile (T3/T14)

    if (kt0 <= bound) {
      // ---- S^T = mfma(K, Q): lane (g,l15) gets keys kb+4g+r at q-col l15 ----
      float sc[2][4][4];
#pragma unroll
      for (int s = 0; s < 4; s++) {
        int kb = kt0 + s * 16;
        bool live = (kb <= bound);
        f32x4 st0 = zero, st1 = zero;
        uint32_t pb = 0;
        if (live) {
          int R = s * 16 + l15, sw = l15 & 7;
          bf16x8 kf0 = *(const bf16x8*)(sK[buf] + R * 128 + ((g ^ sw) << 4));
          bf16x8 kf1 = *(const bf16x8*)(sK[buf] + R * 128 + (((4 + g) ^ sw) << 4));
          st0 = MFMA16(kf0, qf[0][0], st0); st0 = MFMA16(kf1, qf[0][1], st0);
          st1 = MFMA16(kf0, qf[1][0], st1); st1 = MFMA16(kf1, qf[1][1], st1);
          pb = *(const uint32_t*)(pdb + kb + 4 * g);
        }
#pragma unroll
        for (int r = 0; r < 4; r++) {
          int key = kb + 4 * g + r;
          bool pm = (pb >> (8 * r)) & 0xffu;
#pragma unroll
          for (int c = 0; c < 2; c++) {
            int q = qw0 + c * 16 + l15;
            bool msk = !live || pm || (key > q);
            float v = c ? st1[r] : st0[r];
            sc[c][s][r] = msk ? -1e30f : v * SCL;
          }
        }
      }

      // ---- online softmax + P write (per 16-col group) ----
#pragma unroll
      for (int c = 0; c < 2; c++) {
        float m01 = fmaxf(fmaxf(sc[c][0][0], sc[c][0][1]), fmaxf(sc[c][0][2], sc[c][0][3]));
        float m11 = fmaxf(fmaxf(sc[c][1][0], sc[c][1][1]), fmaxf(sc[c][1][2], sc[c][1][3]));
        float m21 = fmaxf(fmaxf(sc[c][2][0], sc[c][2][1]), fmaxf(sc[c][2][2], sc[c][2][3]));
        float m31 = fmaxf(fmaxf(sc[c][3][0], sc[c][3][1]), fmaxf(sc[c][3][2], sc[c][3][3]));
        float mt = fmaxf(fmaxf(m01, m11), fmaxf(m21, m31));
        mt = fmaxf(mt, __shfl_xor(mt, 16));
        mt = fmaxf(mt, __shfl_xor(mt, 32));
        float mnew = fmaxf(mrun[c], mt);
        float al = __builtin_amdgcn_exp2f(mrun[c] - mnew);
        mrun[c] = mnew;
        float rs = 0.f;
        int prow = c * 16 + l15, psw = l15 & 7;
        char* pwb = sP[w] + prow * 128 + (g & 1) * 8;
#pragma unroll
        for (int s = 0; s < 4; s++) {
          float p0 = __builtin_amdgcn_exp2f(sc[c][s][0] - mnew);
          float p1 = __builtin_amdgcn_exp2f(sc[c][s][1] - mnew);
          float p2 = __builtin_amdgcn_exp2f(sc[c][s][2] - mnew);
          float p3 = __builtin_amdgcn_exp2f(sc[c][s][3] - mnew);
          rs += (p0 + p1) + (p2 + p3);
          uint32_t w0 = cvt_pk_bf16(p0, p1), w1 = cvt_pk_bf16(p2, p3);
          char* dst = pwb + (((2 * s + (g >> 1)) ^ psw) << 4);
          *(uint32_t*)dst = w0;
          *(uint32_t*)(dst + 4) = w1;
        }
        rs += __shfl_xor(rs, 16);
        rs += __shfl_xor(rs, 32);
        lrun[c] = lrun[c] * al + rs;
#pragma unroll
        for (int db = 0; db < 4; db++)
#pragma unroll
          for (int r = 0; r < 4; r++) oacc[c][db][r] *= al;
      }

      // ---- PV: O^T += V^T . P^T (A = V^T from LDS, B = P^T from per-wave LDS) ----
#pragma unroll
      for (int kc = 0; kc < 2; kc++) {
        if (kt0 + 32 * kc <= bound) {
          bf16x8 pf[2];
#pragma unroll
          for (int c = 0; c < 2; c++)
            pf[c] = *(const bf16x8*)(sP[w] + (c * 16 + l15) * 128 +
                                     (((4 * kc + g) ^ (l15 & 7)) << 4));
#pragma unroll
          for (int db = 0; db < 4; db++) {
            int dR = db * 16 + l15;
            bf16x8 vf = *(const bf16x8*)(sV[buf] + dR * 128 +
                                         (((4 * kc + g) ^ (dR & 7)) << 4));
            oacc[0][db] = MFMA16(vf, pf[0], oacc[0][db]);
            oacc[1][db] = MFMA16(vf, pf[1], oacc[1][db]);
          }
        }
      }
    }
    __syncthreads();   // drains staged vmcnt + protects buf flip
    buf ^= 1;
  }
#undef STAGE

  // epilogue: lane holds O^T[d = db*16 + g*4 + r][q = qw0 + c*16 + l15]
#pragma unroll
  for (int c = 0; c < 2; c++) {
    float rl = 1.0f / lrun[c];
    int q = qw0 + c * 16 + l15;
    u16* op = Ob + ((size_t)b * L_ + q) * HD_ + h * D_ + g * 4;
#pragma unroll
    for (int db = 0; db < 4; db++) {
      ushort4 pk;
      pk.x = f2bf(oacc[c][db][0] * rl);
      pk.y = f2bf(oacc[c][db][1] * rl);
      pk.z = f2bf(oacc[c][db][2] * rl);
      pk.w = f2bf(oacc[c][db][3] * rl);
      *(ushort4*)(op + db * 16) = pk;
    }
  }
}

extern "C" void kernel_launch(void* const* d_in, const int* in_sizes, int n_in,
                              void* d_out, int out_size, void* d_ws, size_t ws_size,
                              hipStream_t stream) {
  const float* x      = (const float*)d_in[0];
  const float* y      = (const float*)d_in[1];
  const unsigned char* mask = (const unsigned char*)d_in[2];
  const float* Wq_w   = (const float*)d_in[3];
  const float* Wq_b   = (const float*)d_in[4];
  const float* Wkv_w  = (const float*)d_in[5];
  const float* Wkv_b  = (const float*)d_in[6];
  const float* proj_w = (const float*)d_in[7];
  const float* proj_b = (const float*)d_in[8];

  char* ws = (char*)d_ws;
  u16* xb   = (u16*)(ws);                        // 8 MB  (reused as Ob after qkv)
  u16* yb   = (u16*)(ws + (size_t)(8  << 20));   // 8 MB
  u16* Wqt  = (u16*)(ws + (size_t)(16 << 20));   // 2 MB
  u16* Wkvt = (u16*)(ws + (size_t)(18 << 20));   // 4 MB
  u16* Wpt  = (u16*)(ws + (size_t)(22 << 20));   // 2 MB
  u16* Qb   = (u16*)(ws + (size_t)(24 << 20));   // 8 MB
  u16* Kb   = (u16*)(ws + (size_t)(32 << 20));   // 8 MB (V^T follows contiguously)
  u16* Vtb  = (u16*)(ws + (size_t)(40 << 20));   // 8 MB, layout [b,h,d,l]
  u16* Ob   = xb;

  hipLaunchKernelGGL(cast2_k, dim3(4096), dim3(256), 0, stream, x, y, xb, yb);
  hipLaunchKernelGGL(wtrans_k, dim3(64, 32, 3), dim3(256), 0, stream,
                     Wq_w, Wkv_w, proj_w, Wqt, Wkvt, Wpt);
  // fused: Q = xb@Wq+b -> [b,h,l,d]; KV = yb@Wkv+b -> K [b,h,l,d], V^T [b,h,d,l]
  hipLaunchKernelGGL(qkv_k, dim3(24, 32), dim3(256), 0, stream,
                     xb, yb, Wqt, Wkvt, Wq_b, Wkv_b, Qb, Kb);
  hipLaunchKernelGGL(attn_k, dim3(16, H_, B_), dim3(256), 0, stream, Qb, Kb, Vtb, mask, Ob);
  // out = Ob @ proj + b -> f32
  hipLaunchKernelGGL(gemm_k, dim3(8, 32), dim3(256), 0, stream, Ob, Wpt, proj_b, d_out, 1024);
}

// Round 6
// 161.270 us; speedup vs baseline: 2.0043x; 1.0534x over previous
//
#include <hip/hip_runtime.h>
#include <stdint.h>

#define B_  2
#define L_  2048
#define HD_ 1024
#define H_  16
#define D_  64

typedef unsigned short u16;
typedef __attribute__((ext_vector_type(8))) short bf16x8;
typedef __attribute__((ext_vector_type(4))) float f32x4;

#define MFMA16(a, b, c) __builtin_amdgcn_mfma_f32_16x16x32_bf16((a), (b), (c), 0, 0, 0)

__device__ __forceinline__ void gload16(const void* g, void* l) {
  __builtin_amdgcn_global_load_lds((const __attribute__((address_space(1))) void*)g,
                                   (__attribute__((address_space(3))) void*)l, 16, 0, 0);
}

__device__ __forceinline__ u16 f2bf(float f) {
  union { float f; uint32_t u; } c; c.f = f;
  uint32_t u = c.u + 0x7FFFu + ((c.u >> 16) & 1u);
  return (u16)(u >> 16);
}

__device__ __forceinline__ uint32_t cvt_pk_bf16(float lo, float hi) {
  uint32_t r;
  asm("v_cvt_pk_bf16_f32 %0, %1, %2" : "=v"(r) : "v"(lo), "v"(hi));
  return r;
}

// ---------------- fused cast f32 -> bf16 for x and y (8 elems/thread) ----------------
__global__ void cast2_k(const float* __restrict__ x, const float* __restrict__ y,
                        u16* __restrict__ xb, u16* __restrict__ yb) {
  int bid = blockIdx.x;
  const float* in = bid < 2048 ? x : y;
  u16* out = bid < 2048 ? xb : yb;
  int i = ((bid & 2047) * 256 + threadIdx.x) * 8;   // 2048*256*8 == 4M exact
  float4 a = *(const float4*)(in + i);
  float4 b = *(const float4*)(in + i + 4);
  bf16x8 r;
  r[0] = (short)f2bf(a.x); r[1] = (short)f2bf(a.y); r[2] = (short)f2bf(a.z); r[3] = (short)f2bf(a.w);
  r[4] = (short)f2bf(b.x); r[5] = (short)f2bf(b.y); r[6] = (short)f2bf(b.z); r[7] = (short)f2bf(b.w);
  *(bf16x8*)(out + i) = r;
}

// ---------------- fused transpose+cast of all three weights: dst[n][k]=bf16(src[k][n]) ----
// z=0: Wq (N=1024), z=1: Wkv (N=2048), z=2: proj (N=1024). K=1024 for all.
__global__ void wtrans_k(const float* __restrict__ Wq, const float* __restrict__ Wkv,
                         const float* __restrict__ Wp,
                         u16* __restrict__ Wqt, u16* __restrict__ Wkvt, u16* __restrict__ Wpt) {
  int z = blockIdx.z;
  const float* src = z == 0 ? Wq : (z == 1 ? Wkv : Wp);
  u16* dst = z == 0 ? Wqt : (z == 1 ? Wkvt : Wpt);
  int Nfull = (z == 1) ? 2048 : 1024;
  int nb = blockIdx.x * 32;
  if (nb >= Nfull) return;               // block-uniform early out (before any barrier)
  __shared__ float tile[32][33];
  int t = threadIdx.x;
  int tc = t & 31, tr = t >> 5;
  int kb = blockIdx.y * 32;
#pragma unroll
  for (int i = 0; i < 4; i++)
    tile[tr + i * 8][tc] = src[(size_t)(kb + tr + i * 8) * Nfull + nb + tc];
  __syncthreads();
#pragma unroll
  for (int i = 0; i < 4; i++) {
    int nl = tr + i * 8;
    dst[(size_t)(nb + nl) * 1024 + kb + tc] = f2bf(tile[tc][nl]);
  }
}

// ---------------- shared GEMM body: C[m][n] = sum_k A[m][k]*Bt[n][k] + bias[n] ----
// K = 1024 fixed. 128x128 tile, BK=64, 4 waves. LDS rows 128B, slot s at phys s^(r&7).
// epi 0: bf16 out [b,h,l,d].  epi 1: n<1024 -> K [b,h,l,d]; n>=1024 -> V^T [b,h,d,l].
// epi 2: f32 row-major + bias (uses N).
__device__ __forceinline__ void gemm_body(
    char* sA, char* sB,
    const u16* __restrict__ A, const u16* __restrict__ Bt,
    const float* __restrict__ bias, void* __restrict__ outp,
    int N, int epi, int bm, int bn)
{
  int t = threadIdx.x;
  int lane = t & 63, w = t >> 6;
  int g = lane >> 4, l15 = lane & 15;
  int wr = w >> 1, wc = w & 1;

  f32x4 zero = {0.f, 0.f, 0.f, 0.f};
  f32x4 acc[4][4];
#pragma unroll
  for (int mi = 0; mi < 4; mi++)
#pragma unroll
    for (int ni = 0; ni < 4; ni++) acc[mi][ni] = zero;

  for (int kt = 0; kt < 16; kt++) {
    int k0 = kt << 6;
    __syncthreads();
#pragma unroll
    for (int it = 0; it < 4; it++) {
      int c = it * 256 + t;           // 0..1023 16B-chunks per matrix
      int r = c >> 3, sp = c & 7;
      int off = (sp ^ (r & 7)) << 4;  // pre-swizzled global source (T2 both-sides rule)
      gload16((const char*)(A + (size_t)(bm + r) * 1024 + k0) + off, sA + c * 16);
      gload16((const char*)(Bt + (size_t)(bn + r) * 1024 + k0) + off, sB + c * 16);
    }
    __syncthreads();
#pragma unroll
    for (int kc = 0; kc < 2; kc++) {
      bf16x8 af[4], bfr[4];
#pragma unroll
      for (int mi = 0; mi < 4; mi++) {
        int r = wr * 64 + mi * 16 + l15;
        af[mi] = *(const bf16x8*)(sA + r * 128 + (((kc * 4 + g) ^ (r & 7)) << 4));
      }
#pragma unroll
      for (int ni = 0; ni < 4; ni++) {
        int r = wc * 64 + ni * 16 + l15;
        bfr[ni] = *(const bf16x8*)(sB + r * 128 + (((kc * 4 + g) ^ (r & 7)) << 4));
      }
#pragma unroll
      for (int mi = 0; mi < 4; mi++)
#pragma unroll
        for (int ni = 0; ni < 4; ni++)
          acc[mi][ni] = MFMA16(af[mi], bfr[ni], acc[mi][ni]);
    }
  }

  float bv[4];
#pragma unroll
  for (int ni = 0; ni < 4; ni++) bv[ni] = bias[bn + wc * 64 + ni * 16 + l15];

  if (epi == 2) {
    float* fo = (float*)outp;
#pragma unroll
    for (int mi = 0; mi < 4; mi++)
#pragma unroll
      for (int ni = 0; ni < 4; ni++) {
        int n = bn + wc * 64 + ni * 16 + l15;
#pragma unroll
        for (int r = 0; r < 4; r++) {
          int m = bm + wr * 64 + mi * 16 + g * 4 + r;
          fo[(size_t)m * N + n] = acc[mi][ni][r] + bv[ni];
        }
      }
  } else {
    u16* ob = (u16*)outp;
#pragma unroll
    for (int mi = 0; mi < 4; mi++)
#pragma unroll
      for (int ni = 0; ni < 4; ni++) {
        int n = bn + wc * 64 + ni * 16 + l15;
        int kv = n >> 10;          // 0 for epi0 (N=1024)
        int hh = (n >> 6) & 15;
        int dd = n & 63;
        int m0 = bm + wr * 64 + mi * 16 + g * 4;
        int bb = m0 >> 11, lq0 = m0 & 2047;
        if (epi == 1 && kv == 1) {
          // V stored TRANSPOSED: [b,h,d,l]; r -> lq consecutive -> one 8B store
          ushort4 pk;
          pk.x = f2bf(acc[mi][ni][0] + bv[ni]);
          pk.y = f2bf(acc[mi][ni][1] + bv[ni]);
          pk.z = f2bf(acc[mi][ni][2] + bv[ni]);
          pk.w = f2bf(acc[mi][ni][3] + bv[ni]);
          size_t idx = (size_t)(B_ * H_ * L_ * D_) +
                       (((size_t)(bb * H_ + hh) * D_ + dd) * L_ + lq0);
          *(ushort4*)(ob + idx) = pk;
        } else {
#pragma unroll
          for (int r = 0; r < 4; r++) {
            size_t idx = (((size_t)(bb * H_ + hh) * L_ + lq0 + r) * D_) + dd;
            ob[idx] = f2bf(acc[mi][ni][r] + bv[ni]);
          }
        }
      }
  }
}

// fused Q + KV projection: grid (8+16, 32); bx<8 -> Q-GEMM, else KV-GEMM.
__global__ __launch_bounds__(256) void qkv_k(
    const u16* __restrict__ xb, const u16* __restrict__ yb,
    const u16* __restrict__ Wqt, const u16* __restrict__ Wkvt,
    const float* __restrict__ Wq_b, const float* __restrict__ Wkv_b,
    u16* __restrict__ Qout, u16* __restrict__ KVout)
{
  __shared__ char sA[128 * 128];
  __shared__ char sB[128 * 128];
  int bx = blockIdx.x, bm = blockIdx.y * 128;
  if (bx < 8)
    gemm_body(sA, sB, xb, Wqt, Wq_b, (void*)Qout, 1024, 0, bm, bx * 128);
  else
    gemm_body(sA, sB, yb, Wkvt, Wkv_b, (void*)KVout, 2048, 1, bm, (bx - 8) * 128);
}

// proj GEMM (epi2, f32 out)
__global__ __launch_bounds__(256) void gemm_k(
    const u16* __restrict__ A, const u16* __restrict__ Bt,
    const float* __restrict__ bias, void* __restrict__ outp, int N)
{
  __shared__ char sA[128 * 128];
  __shared__ char sB[128 * 128];
  gemm_body(sA, sB, A, Bt, bias, outp, N, 2, blockIdx.y * 128, blockIdx.x * 128);
}

// ---------------- flash attention v5 ----------------
// grid (8,16,2): each block processes TWO q-chunks (qb = 15-bx, then bx) -> every
// block does exactly 36 KV tiles (perfect causal load balance, 256 equal blocks).
// k-loop uses the T3/T4 two-barrier counted-vmcnt pipeline: B1 (WAR safe) ->
// STAGE(next) -> s_waitcnt vmcnt(4) (own tile-t loads done; next-tile 4 stay in
// flight through compute) -> B2 -> compute. vmcnt(0) only on the last tile of a
// pass. Compute body identical to the proven R2/R4 version.
__global__ __launch_bounds__(256, 2) void attn_k(
    const u16* __restrict__ Qb, const u16* __restrict__ Kb, const u16* __restrict__ Vt,
    const unsigned char* __restrict__ pad, u16* __restrict__ Ob)
{
  __shared__ char sK[2][8192];   // [buf][key 0..63][128B row], slot s at phys s^(key&7)
  __shared__ char sV[2][8192];   // [buf][d 0..63][128B row = 64 keys], slot s^(d&7)
  __shared__ char sP[4][4096];   // per-wave P^T: [row c*16+q15][128B = 64 keys], s^(q15&7)
  int t = threadIdx.x, lane = t & 63, w = t >> 6, g = lane >> 4, l15 = lane & 15;
  int h = blockIdx.y, b = blockIdx.z, bh = b * H_ + h;

  const u16* Kbh = Kb + (size_t)bh * L_ * D_;
  const u16* Vbh = Vt + (size_t)bh * D_ * L_;
  const unsigned char* pdb = pad + b * L_;
  const float SCL = 0.125f * 1.44269504089f;  // scale * log2(e); exp via v_exp_f32
  int buf = 0;

#define STAGE(bufi, kt0s) do {                                                        \
    _Pragma("unroll")                                                                 \
    for (int ii = 0; ii < 2; ii++) {                                                  \
      int cc = ii * 256 + t; int rr = cc >> 3, sp = cc & 7;                           \
      int so = (sp ^ (rr & 7)) << 4;                                                  \
      gload16((const char*)(Kbh + (size_t)((kt0s) + rr) * D_) + so, sK[bufi] + cc * 16); \
      gload16((const char*)(Vbh + (size_t)rr * L_ + (kt0s)) + so, sV[bufi] + cc * 16);   \
    } } while (0)

#pragma unroll 1
  for (int pass = 0; pass < 2; pass++) {
    int qb = pass == 0 ? 15 - (int)blockIdx.x : (int)blockIdx.x;
    int qw0 = qb * 128 + w * 32;
    int bound = qw0 + 31;           // last q-row this wave owns
    int nkt = 2 * qb + 2;

    // Q fragments, both 16-col groups: qf[c][dc] covers d = dc*32 + g*8 .. +7
    bf16x8 qf[2][2];
#pragma unroll
    for (int c = 0; c < 2; c++) {
      const u16* qp = Qb + ((size_t)bh * L_ + qw0 + c * 16 + l15) * D_ + g * 8;
      qf[c][0] = *(const bf16x8*)qp;
      qf[c][1] = *(const bf16x8*)(qp + 32);
    }

    f32x4 zero = {0.f, 0.f, 0.f, 0.f};
    f32x4 oacc[2][4];
#pragma unroll
    for (int c = 0; c < 2; c++)
#pragma unroll
      for (int db = 0; db < 4; db++) oacc[c][db] = zero;
    float mrun[2] = {-1e30f, -1e30f}, lrun[2] = {0.f, 0.f};

    if (pass) __syncthreads();      // pass boundary: full drain before buffer reuse
    STAGE(buf, 0);

#pragma unroll 1
    for (int kt = 0; kt < nkt; kt++) {
      int kt0 = kt << 6;
      __builtin_amdgcn_sched_barrier(0);
      __builtin_amdgcn_s_barrier();                    // B1: buf^1 free to overwrite
      if (kt + 1 < nkt) {
        STAGE(buf ^ 1, (kt + 1) << 6);                 // next tile's 4 loads in flight
        asm volatile("s_waitcnt vmcnt(4)" ::: "memory");  // own tile-kt batch landed
      } else {
        asm volatile("s_waitcnt vmcnt(0)" ::: "memory");  // last tile: full drain
      }
      __builtin_amdgcn_s_barrier();                    // B2: tile kt resident block-wide
      __builtin_amdgcn_sched_barrier(0);

      if (kt0 <= bound) {
        // ---- S^T = mfma(K, Q): lane (g,l15) gets keys kb+4g+r at q-col l15 ----
        float sc[2][4][4];
#pragma unroll
        for (int s = 0; s < 4; s++) {
          int kb = kt0 + s * 16;
          bool live = (kb <= bound);
          f32x4 st0 = zero, st1 = zero;
          uint32_t pb = 0;
          if (live) {
            int R = s * 16 + l15, sw = l15 & 7;
            bf16x8 kf0 = *(const bf16x8*)(sK[buf] + R * 128 + ((g ^ sw) << 4));
            bf16x8 kf1 = *(const bf16x8*)(sK[buf] + R * 128 + (((4 + g) ^ sw) << 4));
            st0 = MFMA16(kf0, qf[0][0], st0); st0 = MFMA16(kf1, qf[0][1], st0);
            st1 = MFMA16(kf0, qf[1][0], st1); st1 = MFMA16(kf1, qf[1][1], st1);
            pb = *(const uint32_t*)(pdb + kb + 4 * g);
          }
#pragma unroll
          for (int r = 0; r < 4; r++) {
            int key = kb + 4 * g + r;
            bool pm = (pb >> (8 * r)) & 0xffu;
#pragma unroll
            for (int c = 0; c < 2; c++) {
              int q = qw0 + c * 16 + l15;
              bool msk = !live || pm || (key > q);
              float v = c ? st1[r] : st0[r];
              sc[c][s][r] = msk ? -1e30f : v * SCL;
            }
          }
        }

        // ---- online softmax + P write (per 16-col group) ----
#pragma unroll
        for (int c = 0; c < 2; c++) {
          float m01 = fmaxf(fmaxf(sc[c][0][0], sc[c][0][1]), fmaxf(sc[c][0][2], sc[c][0][3]));
          float m11 = fmaxf(fmaxf(sc[c][1][0], sc[c][1][1]), fmaxf(sc[c][1][2], sc[c][1][3]));
          float m21 = fmaxf(fmaxf(sc[c][2][0], sc[c][2][1]), fmaxf(sc[c][2][2], sc[c][2][3]));
          float m31 = fmaxf(fmaxf(sc[c][3][0], sc[c][3][1]), fmaxf(sc[c][3][2], sc[c][3][3]));
          float mt = fmaxf(fmaxf(m01, m11), fmaxf(m21, m31));
          mt = fmaxf(mt, __shfl_xor(mt, 16));
          mt = fmaxf(mt, __shfl_xor(mt, 32));
          float mnew = fmaxf(mrun[c], mt);
          float al = __builtin_amdgcn_exp2f(mrun[c] - mnew);
          mrun[c] = mnew;
          float rs = 0.f;
          int prow = c * 16 + l15, psw = l15 & 7;
          char* pwb = sP[w] + prow * 128 + (g & 1) * 8;
#pragma unroll
          for (int s = 0; s < 4; s++) {
            float p0 = __builtin_amdgcn_exp2f(sc[c][s][0] - mnew);
            float p1 = __builtin_amdgcn_exp2f(sc[c][s][1] - mnew);
            float p2 = __builtin_amdgcn_exp2f(sc[c][s][2] - mnew);
            float p3 = __builtin_amdgcn_exp2f(sc[c][s][3] - mnew);
            rs += (p0 + p1) + (p2 + p3);
            uint32_t w0 = cvt_pk_bf16(p0, p1), w1 = cvt_pk_bf16(p2, p3);
            char* dst = pwb + (((2 * s + (g >> 1)) ^ psw) << 4);
            *(uint32_t*)dst = w0;
            *(uint32_t*)(dst + 4) = w1;
          }
          rs += __shfl_xor(rs, 16);
          rs += __shfl_xor(rs, 32);
          lrun[c] = lrun[c] * al + rs;
#pragma unroll
          for (int db = 0; db < 4; db++)
#pragma unroll
            for (int r = 0; r < 4; r++) oacc[c][db][r] *= al;
        }

        // ---- PV: O^T += V^T . P^T (A = V^T from LDS, B = P^T from per-wave LDS) ----
#pragma unroll
        for (int kc = 0; kc < 2; kc++) {
          if (kt0 + 32 * kc <= bound) {
            bf16x8 pf[2];
#pragma unroll
            for (int c = 0; c < 2; c++)
              pf[c] = *(const bf16x8*)(sP[w] + (c * 16 + l15) * 128 +
                                       (((4 * kc + g) ^ (l15 & 7)) << 4));
#pragma unroll
            for (int db = 0; db < 4; db++) {
              int dR = db * 16 + l15;
              bf16x8 vf = *(const bf16x8*)(sV[buf] + dR * 128 +
                                           (((4 * kc + g) ^ (dR & 7)) << 4));
              oacc[0][db] = MFMA16(vf, pf[0], oacc[0][db]);
              oacc[1][db] = MFMA16(vf, pf[1], oacc[1][db]);
            }
          }
        }
      }
      buf ^= 1;
    }

    // epilogue: lane holds O^T[d = db*16 + g*4 + r][q = qw0 + c*16 + l15]
#pragma unroll
    for (int c = 0; c < 2; c++) {
      float rl = 1.0f / lrun[c];
      int q = qw0 + c * 16 + l15;
      u16* op = Ob + ((size_t)b * L_ + q) * HD_ + h * D_ + g * 4;
#pragma unroll
      for (int db = 0; db < 4; db++) {
        ushort4 pk;
        pk.x = f2bf(oacc[c][db][0] * rl);
        pk.y = f2bf(oacc[c][db][1] * rl);
        pk.z = f2bf(oacc[c][db][2] * rl);
        pk.w = f2bf(oacc[c][db][3] * rl);
        *(ushort4*)(op + db * 16) = pk;
      }
    }
  }
#undef STAGE
}

extern "C" void kernel_launch(void* const* d_in, const int* in_sizes, int n_in,
                              void* d_out, int out_size, void* d_ws, size_t ws_size,
                              hipStream_t stream) {
  const float* x      = (const float*)d_in[0];
  const float* y      = (const float*)d_in[1];
  const unsigned char* mask = (const unsigned char*)d_in[2];
  const float* Wq_w   = (const float*)d_in[3];
  const float* Wq_b   = (const float*)d_in[4];
  const float* Wkv_w  = (const float*)d_in[5];
  const float* Wkv_b  = (const float*)d_in[6];
  const float* proj_w = (const float*)d_in[7];
  const float* proj_b = (const float*)d_in[8];

  char* ws = (char*)d_ws;
  u16* xb   = (u16*)(ws);                        // 8 MB  (reused as Ob after qkv)
  u16* yb   = (u16*)(ws + (size_t)(8  << 20));   // 8 MB
  u16* Wqt  = (u16*)(ws + (size_t)(16 << 20));   // 2 MB
  u16* Wkvt = (u16*)(ws + (size_t)(18 << 20));   // 4 MB
  u16* Wpt  = (u16*)(ws + (size_t)(22 << 20));   // 2 MB
  u16* Qb   = (u16*)(ws + (size_t)(24 << 20));   // 8 MB
  u16* Kb   = (u16*)(ws + (size_t)(32 << 20));   // 8 MB (V^T follows contiguously)
  u16* Vtb  = (u16*)(ws + (size_t)(40 << 20));   // 8 MB, layout [b,h,d,l]
  u16* Ob   = xb;

  hipLaunchKernelGGL(cast2_k, dim3(4096), dim3(256), 0, stream, x, y, xb, yb);
  hipLaunchKernelGGL(wtrans_k, dim3(64, 32, 3), dim3(256), 0, stream,
                     Wq_w, Wkv_w, proj_w, Wqt, Wkvt, Wpt);
  // fused: Q = xb@Wq+b -> [b,h,l,d]; KV = yb@Wkv+b -> K [b,h,l,d], V^T [b,h,d,l]
  hipLaunchKernelGGL(qkv_k, dim3(24, 32), dim3(256), 0, stream,
                     xb, yb, Wqt, Wkvt, Wq_b, Wkv_b, Qb, Kb);
  hipLaunchKernelGGL(attn_k, dim3(8, H_, B_), dim3(256), 0, stream, Qb, Kb, Vtb, mask, Ob);
  // out = Ob @ proj + b -> f32
  hipLaunchKernelGGL(gemm_k, dim3(8, 32), dim3(256), 0, stream, Ob, Wpt, proj_b, d_out, 1024);
}

// Round 7
// 148.858 us; speedup vs baseline: 2.1714x; 1.0834x over previous
//
#include <hip/hip_runtime.h>
#include <stdint.h>

#define B_  2
#define L_  2048
#define HD_ 1024
#define H_  16
#define D_  64

typedef unsigned short u16;
typedef __attribute__((ext_vector_type(8))) short bf16x8;
typedef __attribute__((ext_vector_type(4))) float f32x4;

#define MFMA16(a, b, c) __builtin_amdgcn_mfma_f32_16x16x32_bf16((a), (b), (c), 0, 0, 0)

__device__ __forceinline__ void gload16(const void* g, void* l) {
  __builtin_amdgcn_global_load_lds((const __attribute__((address_space(1))) void*)g,
                                   (__attribute__((address_space(3))) void*)l, 16, 0, 0);
}

__device__ __forceinline__ u16 f2bf(float f) {
  union { float f; uint32_t u; } c; c.f = f;
  uint32_t u = c.u + 0x7FFFu + ((c.u >> 16) & 1u);
  return (u16)(u >> 16);
}

__device__ __forceinline__ uint32_t cvt_pk_bf16(float lo, float hi) {
  uint32_t r;
  asm("v_cvt_pk_bf16_f32 %0, %1, %2" : "=v"(r) : "v"(lo), "v"(hi));
  return r;
}

// ---------------- fused cast f32 -> bf16 for x and y (8 elems/thread) ----------------
__global__ void cast2_k(const float* __restrict__ x, const float* __restrict__ y,
                        u16* __restrict__ xb, u16* __restrict__ yb) {
  int bid = blockIdx.x;
  const float* in = bid < 2048 ? x : y;
  u16* out = bid < 2048 ? xb : yb;
  int i = ((bid & 2047) * 256 + threadIdx.x) * 8;   // 2048*256*8 == 4M exact
  float4 a = *(const float4*)(in + i);
  float4 b = *(const float4*)(in + i + 4);
  bf16x8 r;
  r[0] = (short)f2bf(a.x); r[1] = (short)f2bf(a.y); r[2] = (short)f2bf(a.z); r[3] = (short)f2bf(a.w);
  r[4] = (short)f2bf(b.x); r[5] = (short)f2bf(b.y); r[6] = (short)f2bf(b.z); r[7] = (short)f2bf(b.w);
  *(bf16x8*)(out + i) = r;
}

// ---------------- fused transpose+cast of all three weights: dst[n][k]=bf16(src[k][n]) ----
// z=0: Wq (N=1024), z=1: Wkv (N=2048), z=2: proj (N=1024). K=1024 for all.
__global__ void wtrans_k(const float* __restrict__ Wq, const float* __restrict__ Wkv,
                         const float* __restrict__ Wp,
                         u16* __restrict__ Wqt, u16* __restrict__ Wkvt, u16* __restrict__ Wpt) {
  int z = blockIdx.z;
  const float* src = z == 0 ? Wq : (z == 1 ? Wkv : Wp);
  u16* dst = z == 0 ? Wqt : (z == 1 ? Wkvt : Wpt);
  int Nfull = (z == 1) ? 2048 : 1024;
  int nb = blockIdx.x * 32;
  if (nb >= Nfull) return;               // block-uniform early out (before any barrier)
  __shared__ float tile[32][33];
  int t = threadIdx.x;
  int tc = t & 31, tr = t >> 5;
  int kb = blockIdx.y * 32;
#pragma unroll
  for (int i = 0; i < 4; i++)
    tile[tr + i * 8][tc] = src[(size_t)(kb + tr + i * 8) * Nfull + nb + tc];
  __syncthreads();
#pragma unroll
  for (int i = 0; i < 4; i++) {
    int nl = tr + i * 8;
    dst[(size_t)(nb + nl) * 1024 + kb + tc] = f2bf(tile[tc][nl]);
  }
}

// ---------------- shared GEMM body: C[m][n] = sum_k A[m][k]*Bt[n][k] + bias[n] ----
// K = 1024 fixed. 128x128 tile, BK=64, 4 waves. LDS rows 128B, slot s at phys s^(r&7).
// epi 0: bf16 out [b,h,l,d].  epi 1: n<1024 -> K [b,h,l,d]; n>=1024 -> V^T [b,h,d,l].
// epi 2: f32 row-major + bias (uses N).
__device__ __forceinline__ void gemm_body(
    char* sA, char* sB,
    const u16* __restrict__ A, const u16* __restrict__ Bt,
    const float* __restrict__ bias, void* __restrict__ outp,
    int N, int epi, int bm, int bn)
{
  int t = threadIdx.x;
  int lane = t & 63, w = t >> 6;
  int g = lane >> 4, l15 = lane & 15;
  int wr = w >> 1, wc = w & 1;

  f32x4 zero = {0.f, 0.f, 0.f, 0.f};
  f32x4 acc[4][4];
#pragma unroll
  for (int mi = 0; mi < 4; mi++)
#pragma unroll
    for (int ni = 0; ni < 4; ni++) acc[mi][ni] = zero;

  for (int kt = 0; kt < 16; kt++) {
    int k0 = kt << 6;
    __syncthreads();
#pragma unroll
    for (int it = 0; it < 4; it++) {
      int c = it * 256 + t;           // 0..1023 16B-chunks per matrix
      int r = c >> 3, sp = c & 7;
      int off = (sp ^ (r & 7)) << 4;  // pre-swizzled global source (T2 both-sides rule)
      gload16((const char*)(A + (size_t)(bm + r) * 1024 + k0) + off, sA + c * 16);
      gload16((const char*)(Bt + (size_t)(bn + r) * 1024 + k0) + off, sB + c * 16);
    }
    __syncthreads();
#pragma unroll
    for (int kc = 0; kc < 2; kc++) {
      bf16x8 af[4], bfr[4];
#pragma unroll
      for (int mi = 0; mi < 4; mi++) {
        int r = wr * 64 + mi * 16 + l15;
        af[mi] = *(const bf16x8*)(sA + r * 128 + (((kc * 4 + g) ^ (r & 7)) << 4));
      }
#pragma unroll
      for (int ni = 0; ni < 4; ni++) {
        int r = wc * 64 + ni * 16 + l15;
        bfr[ni] = *(const bf16x8*)(sB + r * 128 + (((kc * 4 + g) ^ (r & 7)) << 4));
      }
#pragma unroll
      for (int mi = 0; mi < 4; mi++)
#pragma unroll
        for (int ni = 0; ni < 4; ni++)
          acc[mi][ni] = MFMA16(af[mi], bfr[ni], acc[mi][ni]);
    }
  }

  float bv[4];
#pragma unroll
  for (int ni = 0; ni < 4; ni++) bv[ni] = bias[bn + wc * 64 + ni * 16 + l15];

  if (epi == 2) {
    float* fo = (float*)outp;
#pragma unroll
    for (int mi = 0; mi < 4; mi++)
#pragma unroll
      for (int ni = 0; ni < 4; ni++) {
        int n = bn + wc * 64 + ni * 16 + l15;
#pragma unroll
        for (int r = 0; r < 4; r++) {
          int m = bm + wr * 64 + mi * 16 + g * 4 + r;
          fo[(size_t)m * N + n] = acc[mi][ni][r] + bv[ni];
        }
      }
  } else {
    u16* ob = (u16*)outp;
#pragma unroll
    for (int mi = 0; mi < 4; mi++)
#pragma unroll
      for (int ni = 0; ni < 4; ni++) {
        int n = bn + wc * 64 + ni * 16 + l15;
        int kv = n >> 10;          // 0 for epi0 (N=1024)
        int hh = (n >> 6) & 15;
        int dd = n & 63;
        int m0 = bm + wr * 64 + mi * 16 + g * 4;
        int bb = m0 >> 11, lq0 = m0 & 2047;
        if (epi == 1 && kv == 1) {
          // V stored TRANSPOSED: [b,h,d,l]; r -> lq consecutive -> one 8B store
          ushort4 pk;
          pk.x = f2bf(acc[mi][ni][0] + bv[ni]);
          pk.y = f2bf(acc[mi][ni][1] + bv[ni]);
          pk.z = f2bf(acc[mi][ni][2] + bv[ni]);
          pk.w = f2bf(acc[mi][ni][3] + bv[ni]);
          size_t idx = (size_t)(B_ * H_ * L_ * D_) +
                       (((size_t)(bb * H_ + hh) * D_ + dd) * L_ + lq0);
          *(ushort4*)(ob + idx) = pk;
        } else {
#pragma unroll
          for (int r = 0; r < 4; r++) {
            size_t idx = (((size_t)(bb * H_ + hh) * L_ + lq0 + r) * D_) + dd;
            ob[idx] = f2bf(acc[mi][ni][r] + bv[ni]);
          }
        }
      }
  }
}

// fused Q + KV projection: grid (8+16, 32); bx<8 -> Q-GEMM, else KV-GEMM.
__global__ __launch_bounds__(256) void qkv_k(
    const u16* __restrict__ xb, const u16* __restrict__ yb,
    const u16* __restrict__ Wqt, const u16* __restrict__ Wkvt,
    const float* __restrict__ Wq_b, const float* __restrict__ Wkv_b,
    u16* __restrict__ Qout, u16* __restrict__ KVout)
{
  __shared__ char sA[128 * 128];
  __shared__ char sB[128 * 128];
  int bx = blockIdx.x, bm = blockIdx.y * 128;
  if (bx < 8)
    gemm_body(sA, sB, xb, Wqt, Wq_b, (void*)Qout, 1024, 0, bm, bx * 128);
  else
    gemm_body(sA, sB, yb, Wkvt, Wkv_b, (void*)KVout, 2048, 1, bm, (bx - 8) * 128);
}

// proj GEMM (epi2, f32 out)
__global__ __launch_bounds__(256) void gemm_k(
    const u16* __restrict__ A, const u16* __restrict__ Bt,
    const float* __restrict__ bias, void* __restrict__ outp, int N)
{
  __shared__ char sA[128 * 128];
  __shared__ char sB[128 * 128];
  gemm_body(sA, sB, A, Bt, bias, outp, N, 2, blockIdx.y * 128, blockIdx.x * 128);
}

// ---------------- flash attention v6 ----------------
// grid (8,16,2) x 512 threads (8 waves). Each block processes TWO q-chunks
// (qb = 15-bx, then bx) -> exactly 36 KV tiles/block, 256 equal blocks, all
// resident. 8 waves x 16 q-rows = 128 q/chunk -> 2 waves/SIMD so one wave's
// MFMA hides the other's softmax/LDS latency (m114). Two-barrier counted-vmcnt
// k-loop: B1 -> STAGE(next) -> vmcnt(2) -> B2 -> compute; vmcnt(0) only on the
// last tile of a pass. Compute body = proven R2 layout with col-group dim removed.
__global__ __launch_bounds__(512, 2) void attn_k(
    const u16* __restrict__ Qb, const u16* __restrict__ Kb, const u16* __restrict__ Vt,
    const unsigned char* __restrict__ pad, u16* __restrict__ Ob)
{
  __shared__ char sK[2][8192];   // [buf][key 0..63][128B row], slot s at phys s^(key&7)
  __shared__ char sV[2][8192];   // [buf][d 0..63][128B row = 64 keys], slot s^(d&7)
  __shared__ char sP[8][2048];   // per-wave P^T: [q15][128B = 64 keys], slot s^(q15&7)
  int t = threadIdx.x, lane = t & 63, w = t >> 6, g = lane >> 4, l15 = lane & 15;
  int h = blockIdx.y, b = blockIdx.z, bh = b * H_ + h;

  const u16* Kbh = Kb + (size_t)bh * L_ * D_;
  const u16* Vbh = Vt + (size_t)bh * D_ * L_;
  const unsigned char* pdb = pad + b * L_;
  const float SCL = 0.125f * 1.44269504089f;  // scale * log2(e); exp via v_exp_f32
  int buf = 0;
  int psw = l15 & 7;

  // staging (512 threads): 1 K-chunk + 1 V-chunk per thread; chunk t -> row t>>3,
  // 16B slot t&7 (source pre-swizzled, LDS dest linear — T2 both-sides rule)
  int srr = t >> 3, ssp = t & 7;
  int sso = (ssp ^ (srr & 7)) << 4;
#define STAGE(bufi, kt0s) do {                                                        \
    gload16((const char*)(Kbh + (size_t)((kt0s) + srr) * D_) + sso, sK[bufi] + t * 16); \
    gload16((const char*)(Vbh + (size_t)srr * L_ + (kt0s)) + sso, sV[bufi] + t * 16);   \
  } while (0)

#pragma unroll 1
  for (int pass = 0; pass < 2; pass++) {
    int qb = pass == 0 ? 15 - (int)blockIdx.x : (int)blockIdx.x;
    int qw0 = qb * 128 + w * 16;
    int bound = qw0 + 15;           // last q-row this wave owns
    int nkt = 2 * qb + 2;

    // Q fragments: qf[dc] covers d = dc*32 + g*8 .. +7 at q-row qw0 + l15
    const u16* qp = Qb + ((size_t)bh * L_ + qw0 + l15) * D_ + g * 8;
    bf16x8 qf0 = *(const bf16x8*)qp;
    bf16x8 qf1 = *(const bf16x8*)(qp + 32);

    f32x4 zero = {0.f, 0.f, 0.f, 0.f};
    f32x4 oacc[4];
#pragma unroll
    for (int db = 0; db < 4; db++) oacc[db] = zero;
    float mrun = -1e30f, lrun = 0.f;

    if (pass) __syncthreads();      // pass boundary: full drain before buffer reuse
    STAGE(buf, 0);

#pragma unroll 1
    for (int kt = 0; kt < nkt; kt++) {
      int kt0 = kt << 6;
      __builtin_amdgcn_sched_barrier(0);
      __builtin_amdgcn_s_barrier();                    // B1: buf^1 free to overwrite
      if (kt + 1 < nkt) {
        STAGE(buf ^ 1, (kt + 1) << 6);                 // next tile's loads in flight
        asm volatile("s_waitcnt vmcnt(2)" ::: "memory");  // own tile-kt batch landed
      } else {
        asm volatile("s_waitcnt vmcnt(0)" ::: "memory");  // last tile: full drain
      }
      __builtin_amdgcn_s_barrier();                    // B2: tile kt resident block-wide
      __builtin_amdgcn_sched_barrier(0);

      if (kt0 <= bound) {
        // ---- S^T = mfma(K, Q): lane (g,l15) gets keys kb+4g+r at q-col l15 ----
        float sc[4][4];
#pragma unroll
        for (int s = 0; s < 4; s++) {
          int kb = kt0 + s * 16;
          bool live = (kb <= bound);
          f32x4 st = zero;
          uint32_t pb = 0;
          if (live) {
            int R = s * 16 + l15, sw = l15 & 7;
            bf16x8 kf0 = *(const bf16x8*)(sK[buf] + R * 128 + ((g ^ sw) << 4));
            bf16x8 kf1 = *(const bf16x8*)(sK[buf] + R * 128 + (((4 + g) ^ sw) << 4));
            st = MFMA16(kf0, qf0, st);
            st = MFMA16(kf1, qf1, st);
            pb = *(const uint32_t*)(pdb + kb + 4 * g);
          }
#pragma unroll
          for (int r = 0; r < 4; r++) {
            int key = kb + 4 * g + r;
            bool pm = (pb >> (8 * r)) & 0xffu;
            bool msk = !live || pm || (key > qw0 + l15);
            sc[s][r] = msk ? -1e30f : st[r] * SCL;
          }
        }

        // ---- online softmax + P write ----
        float m0 = fmaxf(fmaxf(sc[0][0], sc[0][1]), fmaxf(sc[0][2], sc[0][3]));
        float m1 = fmaxf(fmaxf(sc[1][0], sc[1][1]), fmaxf(sc[1][2], sc[1][3]));
        float m2 = fmaxf(fmaxf(sc[2][0], sc[2][1]), fmaxf(sc[2][2], sc[2][3]));
        float m3 = fmaxf(fmaxf(sc[3][0], sc[3][1]), fmaxf(sc[3][2], sc[3][3]));
        float mt = fmaxf(fmaxf(m0, m1), fmaxf(m2, m3));
        mt = fmaxf(mt, __shfl_xor(mt, 16));
        mt = fmaxf(mt, __shfl_xor(mt, 32));
        float mnew = fmaxf(mrun, mt);
        float al = __builtin_amdgcn_exp2f(mrun - mnew);
        mrun = mnew;
        float rs = 0.f;
        char* pwb = sP[w] + l15 * 128 + (g & 1) * 8;
#pragma unroll
        for (int s = 0; s < 4; s++) {
          float p0 = __builtin_amdgcn_exp2f(sc[s][0] - mnew);
          float p1 = __builtin_amdgcn_exp2f(sc[s][1] - mnew);
          float p2 = __builtin_amdgcn_exp2f(sc[s][2] - mnew);
          float p3 = __builtin_amdgcn_exp2f(sc[s][3] - mnew);
          rs += (p0 + p1) + (p2 + p3);
          uint32_t w0 = cvt_pk_bf16(p0, p1), w1 = cvt_pk_bf16(p2, p3);
          char* dst = pwb + (((2 * s + (g >> 1)) ^ psw) << 4);
          *(uint32_t*)dst = w0;
          *(uint32_t*)(dst + 4) = w1;
        }
        rs += __shfl_xor(rs, 16);
        rs += __shfl_xor(rs, 32);
        lrun = lrun * al + rs;
#pragma unroll
        for (int db = 0; db < 4; db++)
#pragma unroll
          for (int r = 0; r < 4; r++) oacc[db][r] *= al;

        // ---- PV: O^T += V^T . P^T ----
#pragma unroll
        for (int kc = 0; kc < 2; kc++) {
          if (kt0 + 32 * kc <= bound) {
            bf16x8 pf = *(const bf16x8*)(sP[w] + l15 * 128 + (((4 * kc + g) ^ psw) << 4));
#pragma unroll
            for (int db = 0; db < 4; db++) {
              int dR = db * 16 + l15;
              bf16x8 vf = *(const bf16x8*)(sV[buf] + dR * 128 +
                                           (((4 * kc + g) ^ (dR & 7)) << 4));
              oacc[db] = MFMA16(vf, pf, oacc[db]);
            }
          }
        }
      }
      buf ^= 1;
    }

    // epilogue: lane holds O^T[d = db*16 + g*4 + r][q = qw0 + l15]
    float rl = 1.0f / lrun;
    int q = qw0 + l15;
    u16* op = Ob + ((size_t)b * L_ + q) * HD_ + h * D_ + g * 4;
#pragma unroll
    for (int db = 0; db < 4; db++) {
      ushort4 pk;
      pk.x = f2bf(oacc[db][0] * rl);
      pk.y = f2bf(oacc[db][1] * rl);
      pk.z = f2bf(oacc[db][2] * rl);
      pk.w = f2bf(oacc[db][3] * rl);
      *(ushort4*)(op + db * 16) = pk;
    }
  }
#undef STAGE
}

extern "C" void kernel_launch(void* const* d_in, const int* in_sizes, int n_in,
                              void* d_out, int out_size, void* d_ws, size_t ws_size,
                              hipStream_t stream) {
  const float* x      = (const float*)d_in[0];
  const float* y      = (const float*)d_in[1];
  const unsigned char* mask = (const unsigned char*)d_in[2];
  const float* Wq_w   = (const float*)d_in[3];
  const float* Wq_b   = (const float*)d_in[4];
  const float* Wkv_w  = (const float*)d_in[5];
  const float* Wkv_b  = (const float*)d_in[6];
  const float* proj_w = (const float*)d_in[7];
  const float* proj_b = (const float*)d_in[8];

  char* ws = (char*)d_ws;
  u16* xb   = (u16*)(ws);                        // 8 MB  (reused as Ob after qkv)
  u16* yb   = (u16*)(ws + (size_t)(8  << 20));   // 8 MB
  u16* Wqt  = (u16*)(ws + (size_t)(16 << 20));   // 2 MB
  u16* Wkvt = (u16*)(ws + (size_t)(18 << 20));   // 4 MB
  u16* Wpt  = (u16*)(ws + (size_t)(22 << 20));   // 2 MB
  u16* Qb   = (u16*)(ws + (size_t)(24 << 20));   // 8 MB
  u16* Kb   = (u16*)(ws + (size_t)(32 << 20));   // 8 MB (V^T follows contiguously)
  u16* Vtb  = (u16*)(ws + (size_t)(40 << 20));   // 8 MB, layout [b,h,d,l]
  u16* Ob   = xb;

  hipLaunchKernelGGL(cast2_k, dim3(4096), dim3(256), 0, stream, x, y, xb, yb);
  hipLaunchKernelGGL(wtrans_k, dim3(64, 32, 3), dim3(256), 0, stream,
                     Wq_w, Wkv_w, proj_w, Wqt, Wkvt, Wpt);
  // fused: Q = xb@Wq+b -> [b,h,l,d]; KV = yb@Wkv+b -> K [b,h,l,d], V^T [b,h,d,l]
  hipLaunchKernelGGL(qkv_k, dim3(24, 32), dim3(256), 0, stream,
                     xb, yb, Wqt, Wkvt, Wq_b, Wkv_b, Qb, Kb);
  hipLaunchKernelGGL(attn_k, dim3(8, H_, B_), dim3(512), 0, stream, Qb, Kb, Vtb, mask, Ob);
  // out = Ob @ proj + b -> f32
  hipLaunchKernelGGL(gemm_k, dim3(8, 32), dim3(256), 0, stream, Ob, Wpt, proj_b, d_out, 1024);
}

// Round 8
// 140.688 us; speedup vs baseline: 2.2975x; 1.0581x over previous
//
#include <hip/hip_runtime.h>
#include <stdint.h>

#define B_  2
#define L_  2048
#define HD_ 1024
#define H_  16
#define D_  64

typedef unsigned short u16;
typedef __attribute__((ext_vector_type(8))) short bf16x8;
typedef __attribute__((ext_vector_type(4))) float f32x4;

#define MFMA16(a, b, c) __builtin_amdgcn_mfma_f32_16x16x32_bf16((a), (b), (c), 0, 0, 0)

__device__ __forceinline__ void gload16(const void* g, void* l) {
  __builtin_amdgcn_global_load_lds((const __attribute__((address_space(1))) void*)g,
                                   (__attribute__((address_space(3))) void*)l, 16, 0, 0);
}

__device__ __forceinline__ u16 f2bf(float f) {
  union { float f; uint32_t u; } c; c.f = f;
  uint32_t u = c.u + 0x7FFFu + ((c.u >> 16) & 1u);
  return (u16)(u >> 16);
}

__device__ __forceinline__ uint32_t cvt_pk_bf16(float lo, float hi) {
  uint32_t r;
  asm("v_cvt_pk_bf16_f32 %0, %1, %2" : "=v"(r) : "v"(lo), "v"(hi));
  return r;
}

// ---------------- fused cast f32 -> bf16 for x and y (8 elems/thread) ----------------
__global__ void cast2_k(const float* __restrict__ x, const float* __restrict__ y,
                        u16* __restrict__ xb, u16* __restrict__ yb) {
  int bid = blockIdx.x;
  const float* in = bid < 2048 ? x : y;
  u16* out = bid < 2048 ? xb : yb;
  int i = ((bid & 2047) * 256 + threadIdx.x) * 8;   // 2048*256*8 == 4M exact
  float4 a = *(const float4*)(in + i);
  float4 b = *(const float4*)(in + i + 4);
  bf16x8 r;
  r[0] = (short)f2bf(a.x); r[1] = (short)f2bf(a.y); r[2] = (short)f2bf(a.z); r[3] = (short)f2bf(a.w);
  r[4] = (short)f2bf(b.x); r[5] = (short)f2bf(b.y); r[6] = (short)f2bf(b.z); r[7] = (short)f2bf(b.w);
  *(bf16x8*)(out + i) = r;
}

// ---------------- fused transpose+cast of all three weights: dst[n][k]=bf16(src[k][n]) ----
// z=0: Wq (N=1024), z=1: Wkv (N=2048), z=2: proj (N=1024). K=1024 for all.
__global__ void wtrans_k(const float* __restrict__ Wq, const float* __restrict__ Wkv,
                         const float* __restrict__ Wp,
                         u16* __restrict__ Wqt, u16* __restrict__ Wkvt, u16* __restrict__ Wpt) {
  int z = blockIdx.z;
  const float* src = z == 0 ? Wq : (z == 1 ? Wkv : Wp);
  u16* dst = z == 0 ? Wqt : (z == 1 ? Wkvt : Wpt);
  int Nfull = (z == 1) ? 2048 : 1024;
  int nb = blockIdx.x * 32;
  if (nb >= Nfull) return;               // block-uniform early out (before any barrier)
  __shared__ float tile[32][33];
  int t = threadIdx.x;
  int tc = t & 31, tr = t >> 5;
  int kb = blockIdx.y * 32;
#pragma unroll
  for (int i = 0; i < 4; i++)
    tile[tr + i * 8][tc] = src[(size_t)(kb + tr + i * 8) * Nfull + nb + tc];
  __syncthreads();
#pragma unroll
  for (int i = 0; i < 4; i++) {
    int nl = tr + i * 8;
    dst[(size_t)(nb + nl) * 1024 + kb + tc] = f2bf(tile[tc][nl]);
  }
}

// ---------------- shared GEMM body: C[m][n] = sum_k A[m][k]*Bt[n][k] + bias[n] ----
// K = 1024 fixed. 128x128 tile, BK=64, 4 waves. LDS rows 128B, slot s at phys s^(r&7).
// Double-buffered T3/T4 k-loop (proven in attn R5/R6): B1 -> STAGE(next) ->
// vmcnt(8) (own tile's 8 loads landed; next tile's 8 in flight through compute)
// -> B2 -> compute. vmcnt(0) only on the last K-step.
// epi 0: bf16 out [b,h,l,d].  epi 1: n<1024 -> K [b,h,l,d]; n>=1024 -> V^T [b,h,d,l].
// epi 2: f32 row-major + bias (uses N).
__device__ __forceinline__ void gemm_body(
    char* sA, char* sB,                 // each 2*16384 bytes (double-buffered)
    const u16* __restrict__ A, const u16* __restrict__ Bt,
    const float* __restrict__ bias, void* __restrict__ outp,
    int N, int epi, int bm, int bn)
{
  int t = threadIdx.x;
  int lane = t & 63, w = t >> 6;
  int g = lane >> 4, l15 = lane & 15;
  int wr = w >> 1, wc = w & 1;

  f32x4 zero = {0.f, 0.f, 0.f, 0.f};
  f32x4 acc[4][4];
#pragma unroll
  for (int mi = 0; mi < 4; mi++)
#pragma unroll
    for (int ni = 0; ni < 4; ni++) acc[mi][ni] = zero;

#define GSTAGE(bufi, k0s) do {                                                          \
    _Pragma("unroll")                                                                   \
    for (int it = 0; it < 4; it++) {                                                    \
      int c = it * 256 + t;             /* 0..1023 16B-chunks per matrix */             \
      int r = c >> 3, sp = c & 7;                                                       \
      int off = (sp ^ (r & 7)) << 4;    /* pre-swizzled global source (T2) */           \
      gload16((const char*)(A + (size_t)(bm + r) * 1024 + (k0s)) + off,                 \
              sA + (bufi) * 16384 + c * 16);                                            \
      gload16((const char*)(Bt + (size_t)(bn + r) * 1024 + (k0s)) + off,                \
              sB + (bufi) * 16384 + c * 16);                                            \
    } } while (0)

  GSTAGE(0, 0);
  int buf = 0;
#pragma unroll 1
  for (int kt = 0; kt < 16; kt++) {
    __builtin_amdgcn_sched_barrier(0);
    __builtin_amdgcn_s_barrier();                      // B1: buf^1 free to overwrite
    if (kt < 15) {
      GSTAGE(buf ^ 1, (kt + 1) << 6);                  // next tile's 8 loads in flight
      asm volatile("s_waitcnt vmcnt(8)" ::: "memory"); // own tile's batch landed
    } else {
      asm volatile("s_waitcnt vmcnt(0)" ::: "memory"); // last tile: full drain
    }
    __builtin_amdgcn_s_barrier();                      // B2: tile kt resident block-wide
    __builtin_amdgcn_sched_barrier(0);

    const char* cA = sA + buf * 16384;
    const char* cB = sB + buf * 16384;
#pragma unroll
    for (int kc = 0; kc < 2; kc++) {
      bf16x8 af[4], bfr[4];
#pragma unroll
      for (int mi = 0; mi < 4; mi++) {
        int r = wr * 64 + mi * 16 + l15;
        af[mi] = *(const bf16x8*)(cA + r * 128 + (((kc * 4 + g) ^ (r & 7)) << 4));
      }
#pragma unroll
      for (int ni = 0; ni < 4; ni++) {
        int r = wc * 64 + ni * 16 + l15;
        bfr[ni] = *(const bf16x8*)(cB + r * 128 + (((kc * 4 + g) ^ (r & 7)) << 4));
      }
#pragma unroll
      for (int mi = 0; mi < 4; mi++)
#pragma unroll
        for (int ni = 0; ni < 4; ni++)
          acc[mi][ni] = MFMA16(af[mi], bfr[ni], acc[mi][ni]);
    }
    buf ^= 1;
  }
#undef GSTAGE

  float bv[4];
#pragma unroll
  for (int ni = 0; ni < 4; ni++) bv[ni] = bias[bn + wc * 64 + ni * 16 + l15];

  if (epi == 2) {
    float* fo = (float*)outp;
#pragma unroll
    for (int mi = 0; mi < 4; mi++)
#pragma unroll
      for (int ni = 0; ni < 4; ni++) {
        int n = bn + wc * 64 + ni * 16 + l15;
#pragma unroll
        for (int r = 0; r < 4; r++) {
          int m = bm + wr * 64 + mi * 16 + g * 4 + r;
          fo[(size_t)m * N + n] = acc[mi][ni][r] + bv[ni];
        }
      }
  } else {
    u16* ob = (u16*)outp;
#pragma unroll
    for (int mi = 0; mi < 4; mi++)
#pragma unroll
      for (int ni = 0; ni < 4; ni++) {
        int n = bn + wc * 64 + ni * 16 + l15;
        int kv = n >> 10;          // 0 for epi0 (N=1024)
        int hh = (n >> 6) & 15;
        int dd = n & 63;
        int m0 = bm + wr * 64 + mi * 16 + g * 4;
        int bb = m0 >> 11, lq0 = m0 & 2047;
        if (epi == 1 && kv == 1) {
          // V stored TRANSPOSED: [b,h,d,l]; r -> lq consecutive -> one 8B store
          ushort4 pk;
          pk.x = f2bf(acc[mi][ni][0] + bv[ni]);
          pk.y = f2bf(acc[mi][ni][1] + bv[ni]);
          pk.z = f2bf(acc[mi][ni][2] + bv[ni]);
          pk.w = f2bf(acc[mi][ni][3] + bv[ni]);
          size_t idx = (size_t)(B_ * H_ * L_ * D_) +
                       (((size_t)(bb * H_ + hh) * D_ + dd) * L_ + lq0);
          *(ushort4*)(ob + idx) = pk;
        } else {
#pragma unroll
          for (int r = 0; r < 4; r++) {
            size_t idx = (((size_t)(bb * H_ + hh) * L_ + lq0 + r) * D_) + dd;
            ob[idx] = f2bf(acc[mi][ni][r] + bv[ni]);
          }
        }
      }
  }
}

// fused Q + KV projection: grid (8+16, 32); bx<8 -> Q-GEMM, else KV-GEMM.
__global__ __launch_bounds__(256) void qkv_k(
    const u16* __restrict__ xb, const u16* __restrict__ yb,
    const u16* __restrict__ Wqt, const u16* __restrict__ Wkvt,
    const float* __restrict__ Wq_b, const float* __restrict__ Wkv_b,
    u16* __restrict__ Qout, u16* __restrict__ KVout)
{
  __shared__ char sA[2 * 16384];
  __shared__ char sB[2 * 16384];
  int bx = blockIdx.x, bm = blockIdx.y * 128;
  if (bx < 8)
    gemm_body(sA, sB, xb, Wqt, Wq_b, (void*)Qout, 1024, 0, bm, bx * 128);
  else
    gemm_body(sA, sB, yb, Wkvt, Wkv_b, (void*)KVout, 2048, 1, bm, (bx - 8) * 128);
}

// proj GEMM (epi2, f32 out)
__global__ __launch_bounds__(256) void gemm_k(
    const u16* __restrict__ A, const u16* __restrict__ Bt,
    const float* __restrict__ bias, void* __restrict__ outp, int N)
{
  __shared__ char sA[2 * 16384];
  __shared__ char sB[2 * 16384];
  gemm_body(sA, sB, A, Bt, bias, outp, N, 2, blockIdx.y * 128, blockIdx.x * 128);
}

// ---------------- flash attention v7 ----------------
// grid (8,16,2) x 512 threads (8 waves). Each block processes TWO q-chunks
// (qb = 15-bx, then bx) -> exactly 36 KV tiles/block, 256 equal blocks, all
// resident. 8 waves x 16 q-rows = 128 q/chunk -> 2 waves/SIMD. Two-barrier
// counted-vmcnt k-loop. v7: wave-uniform mask fast path — clean sub-tiles
// (no diagonal overlap, no padding) skip the per-score cndmask chain.
__global__ __launch_bounds__(512, 2) void attn_k(
    const u16* __restrict__ Qb, const u16* __restrict__ Kb, const u16* __restrict__ Vt,
    const unsigned char* __restrict__ pad, u16* __restrict__ Ob)
{
  __shared__ char sK[2][8192];   // [buf][key 0..63][128B row], slot s at phys s^(key&7)
  __shared__ char sV[2][8192];   // [buf][d 0..63][128B row = 64 keys], slot s^(d&7)
  __shared__ char sP[8][2048];   // per-wave P^T: [q15][128B = 64 keys], slot s^(q15&7)
  int t = threadIdx.x, lane = t & 63, w = t >> 6, g = lane >> 4, l15 = lane & 15;
  int h = blockIdx.y, b = blockIdx.z, bh = b * H_ + h;

  const u16* Kbh = Kb + (size_t)bh * L_ * D_;
  const u16* Vbh = Vt + (size_t)bh * D_ * L_;
  const unsigned char* pdb = pad + b * L_;
  const float SCL = 0.125f * 1.44269504089f;  // scale * log2(e); exp via v_exp_f32
  int buf = 0;
  int psw = l15 & 7;

  // staging (512 threads): 1 K-chunk + 1 V-chunk per thread; chunk t -> row t>>3,
  // 16B slot t&7 (source pre-swizzled, LDS dest linear — T2 both-sides rule)
  int srr = t >> 3, ssp = t & 7;
  int sso = (ssp ^ (srr & 7)) << 4;
#define STAGE(bufi, kt0s) do {                                                        \
    gload16((const char*)(Kbh + (size_t)((kt0s) + srr) * D_) + sso, sK[bufi] + t * 16); \
    gload16((const char*)(Vbh + (size_t)srr * L_ + (kt0s)) + sso, sV[bufi] + t * 16);   \
  } while (0)

#pragma unroll 1
  for (int pass = 0; pass < 2; pass++) {
    int qb = pass == 0 ? 15 - (int)blockIdx.x : (int)blockIdx.x;
    int qw0 = qb * 128 + w * 16;
    int bound = qw0 + 15;           // last q-row this wave owns
    int nkt = 2 * qb + 2;

    // Q fragments: qf[dc] covers d = dc*32 + g*8 .. +7 at q-row qw0 + l15
    const u16* qp = Qb + ((size_t)bh * L_ + qw0 + l15) * D_ + g * 8;
    bf16x8 qf0 = *(const bf16x8*)qp;
    bf16x8 qf1 = *(const bf16x8*)(qp + 32);

    f32x4 zero = {0.f, 0.f, 0.f, 0.f};
    f32x4 oacc[4];
#pragma unroll
    for (int db = 0; db < 4; db++) oacc[db] = zero;
    float mrun = -1e30f, lrun = 0.f;

    if (pass) __syncthreads();      // pass boundary: full drain before buffer reuse
    STAGE(buf, 0);

#pragma unroll 1
    for (int kt = 0; kt < nkt; kt++) {
      int kt0 = kt << 6;
      __builtin_amdgcn_sched_barrier(0);
      __builtin_amdgcn_s_barrier();                    // B1: buf^1 free to overwrite
      if (kt + 1 < nkt) {
        STAGE(buf ^ 1, (kt + 1) << 6);                 // next tile's loads in flight
        asm volatile("s_waitcnt vmcnt(2)" ::: "memory");  // own tile-kt batch landed
      } else {
        asm volatile("s_waitcnt vmcnt(0)" ::: "memory");  // last tile: full drain
      }
      __builtin_amdgcn_s_barrier();                    // B2: tile kt resident block-wide
      __builtin_amdgcn_sched_barrier(0);

      if (kt0 <= bound) {
        // ---- S^T = mfma(K, Q): lane (g,l15) gets keys kb+4g+r at q-col l15 ----
        float sc[4][4];
#pragma unroll
        for (int s = 0; s < 4; s++) {
          int kb = kt0 + s * 16;
          bool live = (kb <= bound);
          f32x4 st = zero;
          uint32_t pb = 0;
          if (live) {
            int R = s * 16 + l15, sw = l15 & 7;
            bf16x8 kf0 = *(const bf16x8*)(sK[buf] + R * 128 + ((g ^ sw) << 4));
            bf16x8 kf1 = *(const bf16x8*)(sK[buf] + R * 128 + (((4 + g) ^ sw) << 4));
            st = MFMA16(kf0, qf0, st);
            st = MFMA16(kf1, qf1, st);
            pb = *(const uint32_t*)(pdb + kb + 4 * g);
          }
          // wave-uniform fast path: sub-tile fully below diagonal and pad-free
          bool needm = !live || (kb + 15 > qw0) || (__ballot(pb != 0) != 0);
          if (needm) {
#pragma unroll
            for (int r = 0; r < 4; r++) {
              int key = kb + 4 * g + r;
              bool pm = (pb >> (8 * r)) & 0xffu;
              bool msk = !live || pm || (key > qw0 + l15);
              sc[s][r] = msk ? -1e30f : st[r] * SCL;
            }
          } else {
#pragma unroll
            for (int r = 0; r < 4; r++) sc[s][r] = st[r] * SCL;
          }
        }

        // ---- online softmax + P write ----
        float m0 = fmaxf(fmaxf(sc[0][0], sc[0][1]), fmaxf(sc[0][2], sc[0][3]));
        float m1 = fmaxf(fmaxf(sc[1][0], sc[1][1]), fmaxf(sc[1][2], sc[1][3]));
        float m2 = fmaxf(fmaxf(sc[2][0], sc[2][1]), fmaxf(sc[2][2], sc[2][3]));
        float m3 = fmaxf(fmaxf(sc[3][0], sc[3][1]), fmaxf(sc[3][2], sc[3][3]));
        float mt = fmaxf(fmaxf(m0, m1), fmaxf(m2, m3));
        mt = fmaxf(mt, __shfl_xor(mt, 16));
        mt = fmaxf(mt, __shfl_xor(mt, 32));
        float mnew = fmaxf(mrun, mt);
        float al = __builtin_amdgcn_exp2f(mrun - mnew);
        mrun = mnew;
        float rs = 0.f;
        char* pwb = sP[w] + l15 * 128 + (g & 1) * 8;
#pragma unroll
        for (int s = 0; s < 4; s++) {
          float p0 = __builtin_amdgcn_exp2f(sc[s][0] - mnew);
          float p1 = __builtin_amdgcn_exp2f(sc[s][1] - mnew);
          float p2 = __builtin_amdgcn_exp2f(sc[s][2] - mnew);
          float p3 = __builtin_amdgcn_exp2f(sc[s][3] - mnew);
          rs += (p0 + p1) + (p2 + p3);
          uint32_t w0 = cvt_pk_bf16(p0, p1), w1 = cvt_pk_bf16(p2, p3);
          char* dst = pwb + (((2 * s + (g >> 1)) ^ psw) << 4);
          *(uint32_t*)dst = w0;
          *(uint32_t*)(dst + 4) = w1;
        }
        rs += __shfl_xor(rs, 16);
        rs += __shfl_xor(rs, 32);
        lrun = lrun * al + rs;
#pragma unroll
        for (int db = 0; db < 4; db++)
#pragma unroll
          for (int r = 0; r < 4; r++) oacc[db][r] *= al;

        // ---- PV: O^T += V^T . P^T ----
#pragma unroll
        for (int kc = 0; kc < 2; kc++) {
          if (kt0 + 32 * kc <= bound) {
            bf16x8 pf = *(const bf16x8*)(sP[w] + l15 * 128 + (((4 * kc + g) ^ psw) << 4));
#pragma unroll
            for (int db = 0; db < 4; db++) {
              int dR = db * 16 + l15;
              bf16x8 vf = *(const bf16x8*)(sV[buf] + dR * 128 +
                                           (((4 * kc + g) ^ (dR & 7)) << 4));
              oacc[db] = MFMA16(vf, pf, oacc[db]);
            }
          }
        }
      }
      buf ^= 1;
    }

    // epilogue: lane holds O^T[d = db*16 + g*4 + r][q = qw0 + l15]
    float rl = 1.0f / lrun;
    int q = qw0 + l15;
    u16* op = Ob + ((size_t)b * L_ + q) * HD_ + h * D_ + g * 4;
#pragma unroll
    for (int db = 0; db < 4; db++) {
      ushort4 pk;
      pk.x = f2bf(oacc[db][0] * rl);
      pk.y = f2bf(oacc[db][1] * rl);
      pk.z = f2bf(oacc[db][2] * rl);
      pk.w = f2bf(oacc[db][3] * rl);
      *(ushort4*)(op + db * 16) = pk;
    }
  }
#undef STAGE
}

extern "C" void kernel_launch(void* const* d_in, const int* in_sizes, int n_in,
                              void* d_out, int out_size, void* d_ws, size_t ws_size,
                              hipStream_t stream) {
  const float* x      = (const float*)d_in[0];
  const float* y      = (const float*)d_in[1];
  const unsigned char* mask = (const unsigned char*)d_in[2];
  const float* Wq_w   = (const float*)d_in[3];
  const float* Wq_b   = (const float*)d_in[4];
  const float* Wkv_w  = (const float*)d_in[5];
  const float* Wkv_b  = (const float*)d_in[6];
  const float* proj_w = (const float*)d_in[7];
  const float* proj_b = (const float*)d_in[8];

  char* ws = (char*)d_ws;
  u16* xb   = (u16*)(ws);                        // 8 MB  (reused as Ob after qkv)
  u16* yb   = (u16*)(ws + (size_t)(8  << 20));   // 8 MB
  u16* Wqt  = (u16*)(ws + (size_t)(16 << 20));   // 2 MB
  u16* Wkvt = (u16*)(ws + (size_t)(18 << 20));   // 4 MB
  u16* Wpt  = (u16*)(ws + (size_t)(22 << 20));   // 2 MB
  u16* Qb   = (u16*)(ws + (size_t)(24 << 20));   // 8 MB
  u16* Kb   = (u16*)(ws + (size_t)(32 << 20));   // 8 MB (V^T follows contiguously)
  u16* Vtb  = (u16*)(ws + (size_t)(40 << 20));   // 8 MB, layout [b,h,d,l]
  u16* Ob   = xb;

  hipLaunchKernelGGL(cast2_k, dim3(4096), dim3(256), 0, stream, x, y, xb, yb);
  hipLaunchKernelGGL(wtrans_k, dim3(64, 32, 3), dim3(256), 0, stream,
                     Wq_w, Wkv_w, proj_w, Wqt, Wkvt, Wpt);
  // fused: Q = xb@Wq+b -> [b,h,l,d]; KV = yb@Wkv+b -> K [b,h,l,d], V^T [b,h,d,l]
  hipLaunchKernelGGL(qkv_k, dim3(24, 32), dim3(256), 0, stream,
                     xb, yb, Wqt, Wkvt, Wq_b, Wkv_b, Qb, Kb);
  hipLaunchKernelGGL(attn_k, dim3(8, H_, B_), dim3(512), 0, stream, Qb, Kb, Vtb, mask, Ob);
  // out = Ob @ proj + b -> f32
  hipLaunchKernelGGL(gemm_k, dim3(8, 32), dim3(256), 0, stream, Ob, Wpt, proj_b, d_out, 1024);
}

// Round 9
// 136.279 us; speedup vs baseline: 2.3718x; 1.0323x over previous
//
#include <hip/hip_runtime.h>
#include <stdint.h>

#define B_  2
#define L_  2048
#define HD_ 1024
#define H_  16
#define D_  64

typedef unsigned short u16;
typedef __attribute__((ext_vector_type(8))) short bf16x8;
typedef __attribute__((ext_vector_type(4))) float f32x4;

#define MFMA16(a, b, c) __builtin_amdgcn_mfma_f32_16x16x32_bf16((a), (b), (c), 0, 0, 0)

__device__ __forceinline__ void gload16(const void* g, void* l) {
  __builtin_amdgcn_global_load_lds((const __attribute__((address_space(1))) void*)g,
                                   (__attribute__((address_space(3))) void*)l, 16, 0, 0);
}

__device__ __forceinline__ u16 f2bf(float f) {
  union { float f; uint32_t u; } c; c.f = f;
  uint32_t u = c.u + 0x7FFFu + ((c.u >> 16) & 1u);
  return (u16)(u >> 16);
}

__device__ __forceinline__ uint32_t cvt_pk_bf16(float lo, float hi) {
  uint32_t r;
  asm("v_cvt_pk_bf16_f32 %0, %1, %2" : "=v"(r) : "v"(lo), "v"(hi));
  return r;
}

// ---------------- fused cast f32 -> bf16 for x and y (8 elems/thread) ----------------
__global__ void cast2_k(const float* __restrict__ x, const float* __restrict__ y,
                        u16* __restrict__ xb, u16* __restrict__ yb) {
  int bid = blockIdx.x;
  const float* in = bid < 2048 ? x : y;
  u16* out = bid < 2048 ? xb : yb;
  int i = ((bid & 2047) * 256 + threadIdx.x) * 8;   // 2048*256*8 == 4M exact
  float4 a = *(const float4*)(in + i);
  float4 b = *(const float4*)(in + i + 4);
  bf16x8 r;
  r[0] = (short)f2bf(a.x); r[1] = (short)f2bf(a.y); r[2] = (short)f2bf(a.z); r[3] = (short)f2bf(a.w);
  r[4] = (short)f2bf(b.x); r[5] = (short)f2bf(b.y); r[6] = (short)f2bf(b.z); r[7] = (short)f2bf(b.w);
  *(bf16x8*)(out + i) = r;
}

// ---------------- fused transpose+cast of all three weights: dst[n][k]=bf16(src[k][n]) ----
// z=0: Wq (N=1024), z=1: Wkv (N=2048), z=2: proj (N=1024). K=1024 for all.
__global__ void wtrans_k(const float* __restrict__ Wq, const float* __restrict__ Wkv,
                         const float* __restrict__ Wp,
                         u16* __restrict__ Wqt, u16* __restrict__ Wkvt, u16* __restrict__ Wpt) {
  int z = blockIdx.z;
  const float* src = z == 0 ? Wq : (z == 1 ? Wkv : Wp);
  u16* dst = z == 0 ? Wqt : (z == 1 ? Wkvt : Wpt);
  int Nfull = (z == 1) ? 2048 : 1024;
  int nb = blockIdx.x * 32;
  if (nb >= Nfull) return;               // block-uniform early out (before any barrier)
  __shared__ float tile[32][33];
  int t = threadIdx.x;
  int tc = t & 31, tr = t >> 5;
  int kb = blockIdx.y * 32;
#pragma unroll
  for (int i = 0; i < 4; i++)
    tile[tr + i * 8][tc] = src[(size_t)(kb + tr + i * 8) * Nfull + nb + tc];
  __syncthreads();
#pragma unroll
  for (int i = 0; i < 4; i++) {
    int nl = tr + i * 8;
    dst[(size_t)(nb + nl) * 1024 + kb + tc] = f2bf(tile[tc][nl]);
  }
}

// ---------------- shared GEMM body: C[m][n] = sum_k A[m][k]*Bt[n][k] + bias[n] ----
// K = 1024 fixed. 128x128 tile, BK=64, 4 waves. LDS rows 128B, slot s at phys s^(r&7).
// Double-buffered T3/T4 k-loop: B1 -> STAGE(next) -> vmcnt(8) -> B2 -> compute.
// vmcnt(0) only on the last K-step.
// epi 0: bf16 out [b,h,l,d].  epi 1: n<1024 -> K [b,h,l,d]; n>=1024 -> V^T [b,h,d,l].
// epi 2: f32 row-major + bias (uses N).
__device__ __forceinline__ void gemm_body(
    char* sA, char* sB,                 // each 2*16384 bytes (double-buffered)
    const u16* __restrict__ A, const u16* __restrict__ Bt,
    const float* __restrict__ bias, void* __restrict__ outp,
    int N, int epi, int bm, int bn)
{
  int t = threadIdx.x;
  int lane = t & 63, w = t >> 6;
  int g = lane >> 4, l15 = lane & 15;
  int wr = w >> 1, wc = w & 1;

  f32x4 zero = {0.f, 0.f, 0.f, 0.f};
  f32x4 acc[4][4];
#pragma unroll
  for (int mi = 0; mi < 4; mi++)
#pragma unroll
    for (int ni = 0; ni < 4; ni++) acc[mi][ni] = zero;

#define GSTAGE(bufi, k0s) do {                                                          \
    _Pragma("unroll")                                                                   \
    for (int it = 0; it < 4; it++) {                                                    \
      int c = it * 256 + t;             /* 0..1023 16B-chunks per matrix */             \
      int r = c >> 3, sp = c & 7;                                                       \
      int off = (sp ^ (r & 7)) << 4;    /* pre-swizzled global source (T2) */           \
      gload16((const char*)(A + (size_t)(bm + r) * 1024 + (k0s)) + off,                 \
              sA + (bufi) * 16384 + c * 16);                                            \
      gload16((const char*)(Bt + (size_t)(bn + r) * 1024 + (k0s)) + off,                \
              sB + (bufi) * 16384 + c * 16);                                            \
    } } while (0)

  GSTAGE(0, 0);
  int buf = 0;
#pragma unroll 1
  for (int kt = 0; kt < 16; kt++) {
    __builtin_amdgcn_sched_barrier(0);
    __builtin_amdgcn_s_barrier();                      // B1: buf^1 free to overwrite
    if (kt < 15) {
      GSTAGE(buf ^ 1, (kt + 1) << 6);                  // next tile's 8 loads in flight
      asm volatile("s_waitcnt vmcnt(8)" ::: "memory"); // own tile's batch landed
    } else {
      asm volatile("s_waitcnt vmcnt(0)" ::: "memory"); // last tile: full drain
    }
    __builtin_amdgcn_s_barrier();                      // B2: tile kt resident block-wide
    __builtin_amdgcn_sched_barrier(0);

    const char* cA = sA + buf * 16384;
    const char* cB = sB + buf * 16384;
#pragma unroll
    for (int kc = 0; kc < 2; kc++) {
      bf16x8 af[4], bfr[4];
#pragma unroll
      for (int mi = 0; mi < 4; mi++) {
        int r = wr * 64 + mi * 16 + l15;
        af[mi] = *(const bf16x8*)(cA + r * 128 + (((kc * 4 + g) ^ (r & 7)) << 4));
      }
#pragma unroll
      for (int ni = 0; ni < 4; ni++) {
        int r = wc * 64 + ni * 16 + l15;
        bfr[ni] = *(const bf16x8*)(cB + r * 128 + (((kc * 4 + g) ^ (r & 7)) << 4));
      }
#pragma unroll
      for (int mi = 0; mi < 4; mi++)
#pragma unroll
        for (int ni = 0; ni < 4; ni++)
          acc[mi][ni] = MFMA16(af[mi], bfr[ni], acc[mi][ni]);
    }
    buf ^= 1;
  }
#undef GSTAGE

  float bv[4];
#pragma unroll
  for (int ni = 0; ni < 4; ni++) bv[ni] = bias[bn + wc * 64 + ni * 16 + l15];

  if (epi == 2) {
    float* fo = (float*)outp;
#pragma unroll
    for (int mi = 0; mi < 4; mi++)
#pragma unroll
      for (int ni = 0; ni < 4; ni++) {
        int n = bn + wc * 64 + ni * 16 + l15;
#pragma unroll
        for (int r = 0; r < 4; r++) {
          int m = bm + wr * 64 + mi * 16 + g * 4 + r;
          fo[(size_t)m * N + n] = acc[mi][ni][r] + bv[ni];
        }
      }
  } else {
    u16* ob = (u16*)outp;
#pragma unroll
    for (int mi = 0; mi < 4; mi++)
#pragma unroll
      for (int ni = 0; ni < 4; ni++) {
        int n = bn + wc * 64 + ni * 16 + l15;
        int kv = n >> 10;          // 0 for epi0 (N=1024)
        int hh = (n >> 6) & 15;
        int dd = n & 63;
        int m0 = bm + wr * 64 + mi * 16 + g * 4;
        int bb = m0 >> 11, lq0 = m0 & 2047;
        if (epi == 1 && kv == 1) {
          // V stored TRANSPOSED: [b,h,d,l]; r -> lq consecutive -> one 8B store
          ushort4 pk;
          pk.x = f2bf(acc[mi][ni][0] + bv[ni]);
          pk.y = f2bf(acc[mi][ni][1] + bv[ni]);
          pk.z = f2bf(acc[mi][ni][2] + bv[ni]);
          pk.w = f2bf(acc[mi][ni][3] + bv[ni]);
          size_t idx = (size_t)(B_ * H_ * L_ * D_) +
                       (((size_t)(bb * H_ + hh) * D_ + dd) * L_ + lq0);
          *(ushort4*)(ob + idx) = pk;
        } else {
#pragma unroll
          for (int r = 0; r < 4; r++) {
            size_t idx = (((size_t)(bb * H_ + hh) * L_ + lq0 + r) * D_) + dd;
            ob[idx] = f2bf(acc[mi][ni][r] + bv[ni]);
          }
        }
      }
  }
}

// fused Q + KV projection: grid (8+16, 32); bx<8 -> Q-GEMM, else KV-GEMM.
__global__ __launch_bounds__(256) void qkv_k(
    const u16* __restrict__ xb, const u16* __restrict__ yb,
    const u16* __restrict__ Wqt, const u16* __restrict__ Wkvt,
    const float* __restrict__ Wq_b, const float* __restrict__ Wkv_b,
    u16* __restrict__ Qout, u16* __restrict__ KVout)
{
  __shared__ char sA[2 * 16384];
  __shared__ char sB[2 * 16384];
  int bx = blockIdx.x, bm = blockIdx.y * 128;
  if (bx < 8)
    gemm_body(sA, sB, xb, Wqt, Wq_b, (void*)Qout, 1024, 0, bm, bx * 128);
  else
    gemm_body(sA, sB, yb, Wkvt, Wkv_b, (void*)KVout, 2048, 1, bm, (bx - 8) * 128);
}

// proj GEMM (epi2, f32 out)
__global__ __launch_bounds__(256) void gemm_k(
    const u16* __restrict__ A, const u16* __restrict__ Bt,
    const float* __restrict__ bias, void* __restrict__ outp, int N)
{
  __shared__ char sA[2 * 16384];
  __shared__ char sB[2 * 16384];
  gemm_body(sA, sB, A, Bt, bias, outp, N, 2, blockIdx.y * 128, blockIdx.x * 128);
}

// ---------------- flash attention v8 ----------------
// grid (16,16,2) = (chunk-idx x, h, b) -> 512 blocks x 512 threads, ONE q-chunk per
// block. qb = b ? x : 15-x: blocks flat=c and flat=c+256 (same XCD/CU slot under the
// round-robin dispatch heuristic) are complementary -> ~36 tiles per CU, with TWO
// independent blocks per CU (96KB LDS, 16 waves) whose barrier stalls decorrelate
// (m114 cross-block overlap). Heavy chunks (qb=15) dispatch first. Compute body
// identical to the proven R6/R7 chunk body.
__global__ __launch_bounds__(512, 2) void attn_k(
    const u16* __restrict__ Qb, const u16* __restrict__ Kb, const u16* __restrict__ Vt,
    const unsigned char* __restrict__ pad, u16* __restrict__ Ob)
{
  __shared__ char sK[2][8192];   // [buf][key 0..63][128B row], slot s at phys s^(key&7)
  __shared__ char sV[2][8192];   // [buf][d 0..63][128B row = 64 keys], slot s^(d&7)
  __shared__ char sP[8][2048];   // per-wave P^T: [q15][128B = 64 keys], slot s^(q15&7)
  int t = threadIdx.x, lane = t & 63, w = t >> 6, g = lane >> 4, l15 = lane & 15;
  int x = blockIdx.x, h = blockIdx.y, b = blockIdx.z, bh = b * H_ + h;
  int qb = b ? x : 15 - x;        // complementary pairing across the two batch halves

  const u16* Kbh = Kb + (size_t)bh * L_ * D_;
  const u16* Vbh = Vt + (size_t)bh * D_ * L_;
  const unsigned char* pdb = pad + b * L_;
  const float SCL = 0.125f * 1.44269504089f;  // scale * log2(e); exp via v_exp_f32
  int psw = l15 & 7;

  // staging (512 threads): 1 K-chunk + 1 V-chunk per thread; chunk t -> row t>>3,
  // 16B slot t&7 (source pre-swizzled, LDS dest linear — T2 both-sides rule)
  int srr = t >> 3, ssp = t & 7;
  int sso = (ssp ^ (srr & 7)) << 4;
#define STAGE(bufi, kt0s) do {                                                        \
    gload16((const char*)(Kbh + (size_t)((kt0s) + srr) * D_) + sso, sK[bufi] + t * 16); \
    gload16((const char*)(Vbh + (size_t)srr * L_ + (kt0s)) + sso, sV[bufi] + t * 16);   \
  } while (0)

  int qw0 = qb * 128 + w * 16;
  int bound = qw0 + 15;           // last q-row this wave owns
  int nkt = 2 * qb + 2;

  // Q fragments: qf[dc] covers d = dc*32 + g*8 .. +7 at q-row qw0 + l15
  const u16* qp = Qb + ((size_t)bh * L_ + qw0 + l15) * D_ + g * 8;
  bf16x8 qf0 = *(const bf16x8*)qp;
  bf16x8 qf1 = *(const bf16x8*)(qp + 32);

  f32x4 zero = {0.f, 0.f, 0.f, 0.f};
  f32x4 oacc[4];
#pragma unroll
  for (int db = 0; db < 4; db++) oacc[db] = zero;
  float mrun = -1e30f, lrun = 0.f;

  STAGE(0, 0);
  int buf = 0;

#pragma unroll 1
  for (int kt = 0; kt < nkt; kt++) {
    int kt0 = kt << 6;
    __builtin_amdgcn_sched_barrier(0);
    __builtin_amdgcn_s_barrier();                    // B1: buf^1 free to overwrite
    if (kt + 1 < nkt) {
      STAGE(buf ^ 1, (kt + 1) << 6);                 // next tile's loads in flight
      asm volatile("s_waitcnt vmcnt(2)" ::: "memory");  // own tile-kt batch landed
    } else {
      asm volatile("s_waitcnt vmcnt(0)" ::: "memory");  // last tile: full drain
    }
    __builtin_amdgcn_s_barrier();                    // B2: tile kt resident block-wide
    __builtin_amdgcn_sched_barrier(0);

    if (kt0 <= bound) {
      // ---- S^T = mfma(K, Q): lane (g,l15) gets keys kb+4g+r at q-col l15 ----
      float sc[4][4];
#pragma unroll
      for (int s = 0; s < 4; s++) {
        int kb = kt0 + s * 16;
        bool live = (kb <= bound);
        f32x4 st = zero;
        uint32_t pb = 0;
        if (live) {
          int R = s * 16 + l15, sw = l15 & 7;
          bf16x8 kf0 = *(const bf16x8*)(sK[buf] + R * 128 + ((g ^ sw) << 4));
          bf16x8 kf1 = *(const bf16x8*)(sK[buf] + R * 128 + (((4 + g) ^ sw) << 4));
          st = MFMA16(kf0, qf0, st);
          st = MFMA16(kf1, qf1, st);
          pb = *(const uint32_t*)(pdb + kb + 4 * g);
        }
        // wave-uniform fast path: sub-tile fully below diagonal and pad-free
        bool needm = !live || (kb + 15 > qw0) || (__ballot(pb != 0) != 0);
        if (needm) {
#pragma unroll
          for (int r = 0; r < 4; r++) {
            int key = kb + 4 * g + r;
            bool pm = (pb >> (8 * r)) & 0xffu;
            bool msk = !live || pm || (key > qw0 + l15);
            sc[s][r] = msk ? -1e30f : st[r] * SCL;
          }
        } else {
#pragma unroll
          for (int r = 0; r < 4; r++) sc[s][r] = st[r] * SCL;
        }
      }

      // ---- online softmax + P write ----
      float m0 = fmaxf(fmaxf(sc[0][0], sc[0][1]), fmaxf(sc[0][2], sc[0][3]));
      float m1 = fmaxf(fmaxf(sc[1][0], sc[1][1]), fmaxf(sc[1][2], sc[1][3]));
      float m2 = fmaxf(fmaxf(sc[2][0], sc[2][1]), fmaxf(sc[2][2], sc[2][3]));
      float m3 = fmaxf(fmaxf(sc[3][0], sc[3][1]), fmaxf(sc[3][2], sc[3][3]));
      float mt = fmaxf(fmaxf(m0, m1), fmaxf(m2, m3));
      mt = fmaxf(mt, __shfl_xor(mt, 16));
      mt = fmaxf(mt, __shfl_xor(mt, 32));
      float mnew = fmaxf(mrun, mt);
      float al = __builtin_amdgcn_exp2f(mrun - mnew);
      mrun = mnew;
      float rs = 0.f;
      char* pwb = sP[w] + l15 * 128 + (g & 1) * 8;
#pragma unroll
      for (int s = 0; s < 4; s++) {
        float p0 = __builtin_amdgcn_exp2f(sc[s][0] - mnew);
        float p1 = __builtin_amdgcn_exp2f(sc[s][1] - mnew);
        float p2 = __builtin_amdgcn_exp2f(sc[s][2] - mnew);
        float p3 = __builtin_amdgcn_exp2f(sc[s][3] - mnew);
        rs += (p0 + p1) + (p2 + p3);
        uint32_t w0 = cvt_pk_bf16(p0, p1), w1 = cvt_pk_bf16(p2, p3);
        char* dst = pwb + (((2 * s + (g >> 1)) ^ psw) << 4);
        *(uint32_t*)dst = w0;
        *(uint32_t*)(dst + 4) = w1;
      }
      rs += __shfl_xor(rs, 16);
      rs += __shfl_xor(rs, 32);
      lrun = lrun * al + rs;
#pragma unroll
      for (int db = 0; db < 4; db++)
#pragma unroll
        for (int r = 0; r < 4; r++) oacc[db][r] *= al;

      // ---- PV: O^T += V^T . P^T ----
#pragma unroll
      for (int kc = 0; kc < 2; kc++) {
        if (kt0 + 32 * kc <= bound) {
          bf16x8 pf = *(const bf16x8*)(sP[w] + l15 * 128 + (((4 * kc + g) ^ psw) << 4));
#pragma unroll
          for (int db = 0; db < 4; db++) {
            int dR = db * 16 + l15;
            bf16x8 vf = *(const bf16x8*)(sV[buf] + dR * 128 +
                                         (((4 * kc + g) ^ (dR & 7)) << 4));
            oacc[db] = MFMA16(vf, pf, oacc[db]);
          }
        }
      }
    }
    buf ^= 1;
  }

  // epilogue: lane holds O^T[d = db*16 + g*4 + r][q = qw0 + l15]
  float rl = 1.0f / lrun;
  int q = qw0 + l15;
  u16* op = Ob + ((size_t)b * L_ + q) * HD_ + h * D_ + g * 4;
#pragma unroll
  for (int db = 0; db < 4; db++) {
    ushort4 pk;
    pk.x = f2bf(oacc[db][0] * rl);
    pk.y = f2bf(oacc[db][1] * rl);
    pk.z = f2bf(oacc[db][2] * rl);
    pk.w = f2bf(oacc[db][3] * rl);
    *(ushort4*)(op + db * 16) = pk;
  }
#undef STAGE
}

extern "C" void kernel_launch(void* const* d_in, const int* in_sizes, int n_in,
                              void* d_out, int out_size, void* d_ws, size_t ws_size,
                              hipStream_t stream) {
  const float* x      = (const float*)d_in[0];
  const float* y      = (const float*)d_in[1];
  const unsigned char* mask = (const unsigned char*)d_in[2];
  const float* Wq_w   = (const float*)d_in[3];
  const float* Wq_b   = (const float*)d_in[4];
  const float* Wkv_w  = (const float*)d_in[5];
  const float* Wkv_b  = (const float*)d_in[6];
  const float* proj_w = (const float*)d_in[7];
  const float* proj_b = (const float*)d_in[8];

  char* ws = (char*)d_ws;
  u16* xb   = (u16*)(ws);                        // 8 MB  (reused as Ob after qkv)
  u16* yb   = (u16*)(ws + (size_t)(8  << 20));   // 8 MB
  u16* Wqt  = (u16*)(ws + (size_t)(16 << 20));   // 2 MB
  u16* Wkvt = (u16*)(ws + (size_t)(18 << 20));   // 4 MB
  u16* Wpt  = (u16*)(ws + (size_t)(22 << 20));   // 2 MB
  u16* Qb   = (u16*)(ws + (size_t)(24 << 20));   // 8 MB
  u16* Kb   = (u16*)(ws + (size_t)(32 << 20));   // 8 MB (V^T follows contiguously)
  u16* Vtb  = (u16*)(ws + (size_t)(40 << 20));   // 8 MB, layout [b,h,d,l]
  u16* Ob   = xb;

  hipLaunchKernelGGL(cast2_k, dim3(4096), dim3(256), 0, stream, x, y, xb, yb);
  hipLaunchKernelGGL(wtrans_k, dim3(64, 32, 3), dim3(256), 0, stream,
                     Wq_w, Wkv_w, proj_w, Wqt, Wkvt, Wpt);
  // fused: Q = xb@Wq+b -> [b,h,l,d]; KV = yb@Wkv+b -> K [b,h,l,d], V^T [b,h,d,l]
  hipLaunchKernelGGL(qkv_k, dim3(24, 32), dim3(256), 0, stream,
                     xb, yb, Wqt, Wkvt, Wq_b, Wkv_b, Qb, Kb);
  hipLaunchKernelGGL(attn_k, dim3(16, H_, B_), dim3(512), 0, stream, Qb, Kb, Vtb, mask, Ob);
  // out = Ob @ proj + b -> f32
  hipLaunchKernelGGL(gemm_k, dim3(8, 32), dim3(256), 0, stream, Ob, Wpt, proj_b, d_out, 1024);
}